// Round 7
// baseline (2569.739 us; speedup 1.0000x reference)
//
#include <hip/hip_runtime.h>
#include <hip/hip_bf16.h>
#include <stdint.h>

// ContinuousEpisodicVLM: 3-step episodic retrieval loop.
// bf16 MFMA candidate generation (sampled-threshold filter) + bf16-top-64
// preselect + exact f32 rescore + exact top-50 softmax message.
// Mode-0 GEMM: 256x256 tile, 8 waves, BK=64, 2-K-tile double-buffered phase
// pipeline (stages issued ~4 phases before the boundary drain), setprio(1)
// around MFMA clusters. Modes 1/2 keep the proven 128^2 single-buffer kernel.

typedef __attribute__((ext_vector_type(8))) short short8;
typedef __attribute__((ext_vector_type(4))) float f32x4;

#define DIM    768
#define NPATCH 2048
#define NMEM   65536
#define NCLS   1000
#define NSAMP  4096   // sample = first 4096 rows
#define CAP    1024   // candidate buffer per patch
#define PRESEL 64     // bf16-score preselection width
#define TAUINV 50.0f  // 1/0.02

__device__ __forceinline__ unsigned short f2bf(float f){
  unsigned b = __float_as_uint(f);
  b += 0x7FFFu + ((b >> 16) & 1u);      // RNE
  return (unsigned short)(b >> 16);
}
__device__ __forceinline__ unsigned encf(float x){
  unsigned b = __float_as_uint(x);
  return (b & 0x80000000u) ? ~b : (b | 0x80000000u);
}
__device__ __forceinline__ float decf(unsigned k){
  unsigned b = (k & 0x80000000u) ? (k & 0x7FFFFFFFu) : ~k;
  return __uint_as_float(b);
}
__device__ __forceinline__ void gload16(const void* g, void* l){
  __builtin_amdgcn_global_load_lds(
      (const __attribute__((address_space(1))) unsigned int*)g,
      (__attribute__((address_space(3))) unsigned int*)l, 16, 0, 0);
}
__device__ __forceinline__ uint4 pack8(float4 a, float4 b){
  uint4 u;
  u.x = (unsigned)f2bf(a.x) | ((unsigned)f2bf(a.y) << 16);
  u.y = (unsigned)f2bf(a.z) | ((unsigned)f2bf(a.w) << 16);
  u.z = (unsigned)f2bf(b.x) | ((unsigned)f2bf(b.y) << 16);
  u.w = (unsigned)f2bf(b.z) | ((unsigned)f2bf(b.w) << 16);
  return u;
}

// ---------------- protos + anchors_bf16 (pre-swizzled) ----------------
__global__ __launch_bounds__(256) void proto_kernel(
    const float* __restrict__ anchors, const float* __restrict__ sums,
    const float* __restrict__ counts, float* __restrict__ protos,
    unsigned short* __restrict__ anchors_bf)
{
  int c = blockIdx.x, t = threadIdx.x;
  if (c >= NCLS){  // pad rows 1000..1023 with zeros
    for (int j = 0; j < 3; ++j) anchors_bf[(size_t)c*DIM + t + j*256] = 0;
    return;
  }
  __shared__ float wv[4]; __shared__ float bc;
  float cnt = fmaxf(counts[c], 1.0f);
  float v[3];
  #pragma unroll
  for (int j = 0; j < 3; ++j) v[j] = sums[(size_t)c*DIM + t + j*256] / cnt;
  float ss = v[0]*v[0] + v[1]*v[1] + v[2]*v[2];
  for (int off = 32; off > 0; off >>= 1) ss += __shfl_down(ss, off, 64);
  if ((t & 63) == 0) wv[t >> 6] = ss;
  __syncthreads();
  if (t == 0) bc = wv[0] + wv[1] + wv[2] + wv[3];
  __syncthreads();
  float rn = 1.0f / fmaxf(sqrtf(bc), 1e-12f);
  __syncthreads();
  float pr[3];
  #pragma unroll
  for (int j = 0; j < 3; ++j){
    int d = t + j*256;
    float a = anchors[(size_t)c*DIM + d];
    pr[j] = a + v[j] * rn;                         // ALPHA = 1.0
    int dd = (d & ~63) | ((((d >> 3) ^ c) & 7) << 3) | (d & 7);
    anchors_bf[(size_t)c*DIM + dd] = f2bf(a);
  }
  ss = pr[0]*pr[0] + pr[1]*pr[1] + pr[2]*pr[2];
  for (int off = 32; off > 0; off >>= 1) ss += __shfl_down(ss, off, 64);
  if ((t & 63) == 0) wv[t >> 6] = ss;
  __syncthreads();
  if (t == 0) bc = wv[0] + wv[1] + wv[2] + wv[3];
  __syncthreads();
  float rn2 = 1.0f / fmaxf(sqrtf(bc), 1e-12f);
  #pragma unroll
  for (int j = 0; j < 3; ++j) protos[(size_t)c*DIM + t + j*256] = pr[j] * rn2;
}

// ---------------- patches f32 working copy ----------------
__global__ __launch_bounds__(256) void prep_patches(
    const float* __restrict__ tp, float* __restrict__ pc)
{
  size_t i = (size_t)blockIdx.x*256 + threadIdx.x;
  *(float4*)(pc + i*4) = *(const float4*)(tp + i*4);
}

// ---------------- f32 -> bf16 pre-swizzled conversion ----------------
__global__ __launch_bounds__(256) void conv_kernel(
    const float* __restrict__ src, unsigned short* __restrict__ dst)
{
  int id = blockIdx.x*256 + threadIdx.x;   // one per 64-elem block
  int row = id / 12, blk = id % 12;
  const float4* s = (const float4*)(src + (size_t)row*DIM + blk*64);
  unsigned short* drow = dst + (size_t)row*DIM + blk*64;
  int key = row & 7;
  #pragma unroll
  for (int c8 = 0; c8 < 8; ++c8){
    uint4 u = pack8(s[c8*2], s[c8*2+1]);
    *(uint4*)(drow + (c8 ^ key)*8) = u;
  }
}

// ---------------- initial K-major swizzled patch slab [12][2048][64] ----------------
__global__ __launch_bounds__(192) void slab_kernel(
    const float* __restrict__ pc, unsigned short* __restrict__ slab)
{
  int b = blockIdx.x, t = threadIdx.x;
  int p = b*2 + (t >= 96 ? 1 : 0);
  int q = (t >= 96) ? t - 96 : t;
  int ks = q >> 3, c8 = q & 7;
  const float* s = pc + (size_t)p*DIM + ks*64 + c8*8;
  uint4 u = pack8(*(const float4*)s, *(const float4*)(s + 4));
  *(uint4*)((char*)slab + (((size_t)ks*NPATCH + p)*128) + ((size_t)(c8 ^ (p & 7))*16)) = u;
}

// ---------------- 256x256 phase-pipelined MFMA GEMM (MODE 0 only) ----------------
// filter >= th, append idx+score. 8 waves (2M x 4N), per-wave 128x64 output.
__global__ __launch_bounds__(512, 2) void gemm256_kernel(
    const unsigned short* __restrict__ Abf, int rowbase,
    const unsigned short* __restrict__ Bslab,
    const float* __restrict__ thresholds,
    int* __restrict__ counters,
    int* __restrict__ cand_idx,
    float* __restrict__ cand_score,
    const int* __restrict__ active)
{
  if (*active == 0) return;
  __shared__ __align__(16) unsigned short Al[2][256*64];
  __shared__ __align__(16) unsigned short Bl[2][256*64];
  int b = blockIdx.x, nwg = gridDim.x;       // 1920, %8==0
  int wg = (b & 7)*(nwg >> 3) + (b >> 3);    // XCD-chunked swizzle
  int mt = wg >> 3, pt = wg & 7;             // pt inner -> A-tile L2 share
  int t = threadIdx.x, w = t >> 6, lane = t & 63, l15 = lane & 15, l4 = lane >> 4;
  int wr = w >> 2, wc = w & 3;
  int pbase = pt*256;
  size_t arow0 = (size_t)rowbase + (size_t)mt*256;

  const char* Ab = (const char*)Abf;
  const char* Bb = (const char*)Bslab;

  float thv[4];
  #pragma unroll
  for (int n = 0; n < 4; ++n) thv[n] = thresholds[pbase + wc*64 + n*16 + l15];

  f32x4 acc[8][4];
  #pragma unroll
  for (int m = 0; m < 8; ++m)
    #pragma unroll
    for (int n = 0; n < 4; ++n) acc[m][n] = (f32x4){0.f, 0.f, 0.f, 0.f};

  // prologue: stage K-tile 0 into buffer 0 (LDS dest linear: id*16)
  #pragma unroll
  for (int j = 0; j < 4; ++j){
    int id = t + j*512;
    gload16(Ab + (arow0 + (id >> 3))*(size_t)(DIM*2) + (id & 7)*16,
            (char*)Al[0] + id*16);
    gload16(Bb + ((size_t)(pbase + (id >> 3)))*128 + (id & 7)*16,
            (char*)Bl[0] + id*16);
  }
  __syncthreads();   // vmcnt(0) drain + barrier

  for (int ks = 0; ks < 12; ++ks){
    int cur = ks & 1, nxt = cur ^ 1;
    // preload B fragments for this K-tile (shared across all 4 phases)
    short8 bfr[4][2];
    #pragma unroll
    for (int n = 0; n < 4; ++n)
      #pragma unroll
      for (int kk = 0; kk < 2; ++kk){
        int row = wc*64 + n*16 + l15;
        int slot = (kk*4 + l4) ^ (row & 7);
        bfr[n][kk] = *(const short8*)((const char*)Bl[cur] + row*128 + slot*16);
      }
    #pragma unroll
    for (int q = 0; q < 4; ++q){
      short8 af[2][2];
      #pragma unroll
      for (int mm = 0; mm < 2; ++mm)
        #pragma unroll
        for (int kk = 0; kk < 2; ++kk){
          int row = wr*128 + (q*2 + mm)*16 + l15;
          int slot = (kk*4 + l4) ^ (row & 7);
          af[mm][kk] = *(const short8*)((const char*)Al[cur] + row*128 + slot*16);
        }
      if (ks < 11){   // issue 2 of 8 stage-loads for K-tile ks+1 (other buffer)
        int id = t + q*512;
        gload16(Ab + (arow0 + (id >> 3))*(size_t)(DIM*2) + (ks + 1)*128 + (id & 7)*16,
                (char*)Al[nxt] + id*16);
        gload16(Bb + (((size_t)(ks + 1))*NPATCH + pbase + (id >> 3))*128 + (id & 7)*16,
                (char*)Bl[nxt] + id*16);
      }
      __builtin_amdgcn_s_setprio(1);
      #pragma unroll
      for (int kk = 0; kk < 2; ++kk)
        #pragma unroll
        for (int mm = 0; mm < 2; ++mm)
          #pragma unroll
          for (int n = 0; n < 4; ++n)
            acc[q*2 + mm][n] = __builtin_amdgcn_mfma_f32_16x16x32_bf16(
                af[mm][kk], bfr[n][kk], acc[q*2 + mm][n], 0, 0, 0);
      __builtin_amdgcn_s_setprio(0);
      __builtin_amdgcn_s_barrier();   // phase cohesion (perf only; data stable)
    }
    __syncthreads();   // boundary: vmcnt(0) drain (loads issued ~4 phases ago) + barrier
  }

  // epilogue: C frag col(l15)=patch, row(l4*4+i)=node
  #pragma unroll
  for (int n = 0; n < 4; ++n){
    int patch = pbase + wc*64 + n*16 + l15;
    float th = thv[n];
    #pragma unroll
    for (int m = 0; m < 8; ++m){
      #pragma unroll
      for (int i = 0; i < 4; ++i){
        float v = acc[m][n][i];
        if (v >= th){
          int node = (int)arow0 + wr*128 + m*16 + l4*4 + i;
          int pos = atomicAdd(&counters[patch], 1);
          if (pos < CAP){
            cand_idx[(size_t)patch*CAP + pos]   = node;
            cand_score[(size_t)patch*CAP + pos] = v;
          }
        }
      }
    }
  }
}

// ---------------- 128x128 single-buffer MFMA GEMM (modes 1,2) ----------------
// MODE 1: A=mbf rows 0..4095, write sims_sample[patch][node]
// MODE 2: A=anchors_bf (rows>=1000 zero), atomicMax evidence
template<int MODE>
__global__ __launch_bounds__(256, 3) void gemm_kernel(
    const unsigned short* __restrict__ Abf,
    const unsigned short* __restrict__ Bslab,
    float* __restrict__ sims_sample,
    unsigned* __restrict__ ev_key,
    const int* __restrict__ active)
{
  if (*active == 0) return;
  __shared__ __align__(16) unsigned short Al[128*64];
  __shared__ __align__(16) unsigned short Bl[128*64];
  int b = blockIdx.x, nwg = gridDim.x;
  int wg = (b & 7)*(nwg >> 3) + (b >> 3);   // XCD-chunked swizzle (nwg%8==0)
  int mt = wg >> 4, pt = wg & 15;
  int t = threadIdx.x, w = t >> 6, lane = t & 63, l15 = lane & 15, l4 = lane >> 4;
  int wr = w >> 1, wc = w & 1;
  int pbase = pt*128;
  int srow = w*8 + (lane >> 3);
  int scol = (lane & 7)*16;

  const char* Ab = (const char*)Abf;
  const char* Bb = (const char*)Bslab;

  f32x4 acc[4][4];
  #pragma unroll
  for (int x = 0; x < 4; ++x)
    #pragma unroll
    for (int y = 0; y < 4; ++y) acc[x][y] = (f32x4){0.f, 0.f, 0.f, 0.f};

  for (int s = 0; s < 12; ++s){
    if (s) __syncthreads();
    size_t arow0 = (size_t)mt*128;
    #pragma unroll
    for (int i = 0; i < 4; ++i){
      const void* ga = Ab + ((arow0 + srow + i*32)*(size_t)(DIM*2)) + s*128 + scol;
      gload16(ga, (char*)Al + i*4096 + w*1024);
      const void* gb = Bb + (((size_t)s*NPATCH + pbase)*128) + i*4096 + w*1024 + lane*16;
      gload16(gb, (char*)Bl + i*4096 + w*1024);
    }
    __syncthreads();

    short8 af[2][4], bf_[2][4];
    #pragma unroll
    for (int kk = 0; kk < 2; ++kk){
      #pragma unroll
      for (int ng = 0; ng < 4; ++ng){
        int row = wr*64 + ng*16 + l15;
        int slot = (kk*4 + l4) ^ (row & 7);
        af[kk][ng] = *(const short8*)((const char*)Al + row*128 + slot*16);
      }
      #pragma unroll
      for (int g = 0; g < 4; ++g){
        int row = wc*64 + g*16 + l15;
        int slot = (kk*4 + l4) ^ (row & 7);
        bf_[kk][g] = *(const short8*)((const char*)Bl + row*128 + slot*16);
      }
    }
    #pragma unroll
    for (int kk = 0; kk < 2; ++kk)
      #pragma unroll
      for (int ng = 0; ng < 4; ++ng)
        #pragma unroll
        for (int g = 0; g < 4; ++g)
          acc[ng][g] = __builtin_amdgcn_mfma_f32_16x16x32_bf16(af[kk][ng], bf_[kk][g], acc[ng][g], 0, 0, 0);
  }

  if (MODE == 1){
    #pragma unroll
    for (int g = 0; g < 4; ++g){
      int patch = pbase + wc*64 + g*16 + l15;
      #pragma unroll
      for (int ng = 0; ng < 4; ++ng){
        int col = mt*128 + wr*64 + ng*16 + l4*4;
        *(f32x4*)(sims_sample + (size_t)patch*NSAMP + col) = acc[ng][g];
      }
    }
  } else {
    #pragma unroll
    for (int g = 0; g < 4; ++g){
      int patch = pbase + wc*64 + g*16 + l15;
      float m = -3e38f; bool any = false;
      #pragma unroll
      for (int ng = 0; ng < 4; ++ng){
        #pragma unroll
        for (int i = 0; i < 4; ++i){
          int a = mt*128 + wr*64 + ng*16 + l4*4 + i;
          if (a < NCLS){ m = fmaxf(m, acc[ng][g][i]); any = true; }
        }
      }
      if (any) atomicMax(&ev_key[patch], encf(m));
    }
  }
}

// -- threshold = 16th max of sampled sims; seed candidates; init cnt + evk --
__global__ __launch_bounds__(256) void thresh_kernel(
    const float* __restrict__ sims, float* __restrict__ thresholds,
    int* __restrict__ counters, int* __restrict__ cand_idx,
    float* __restrict__ cand_score, unsigned* __restrict__ ev_key,
    const int* __restrict__ active)
{
  if (*active == 0) return;
  __shared__ float s[NSAMP];
  __shared__ float wv[4]; __shared__ int wi[4];
  __shared__ float tv16[16]; __shared__ int ti16[16];
  __shared__ float result;
  __shared__ int lcnt;
  int p = blockIdx.x, t = threadIdx.x;
  const float4* src = (const float4*)(sims + (size_t)p*NSAMP);
  for (int i = t; i < NSAMP/4; i += 256) *(float4*)&s[i*4] = src[i];
  __syncthreads();
  for (int r = 0; r < 16; ++r){
    float v = -3e38f; int idx = 0;
    #pragma unroll
    for (int j = 0; j < 16; ++j){
      int ii = t*16 + j; float x = s[ii];
      if (x > v){ v = x; idx = ii; }
    }
    for (int off = 32; off > 0; off >>= 1){
      float ov = __shfl_down(v, off, 64); int oi = __shfl_down(idx, off, 64);
      if (ov > v || (ov == v && oi < idx)){ v = ov; idx = oi; }
    }
    if ((t & 63) == 0){ wv[t >> 6] = v; wi[t >> 6] = idx; }
    __syncthreads();
    if (t == 0){
      float bv = wv[0]; int bi = wi[0];
      for (int q = 1; q < 4; ++q)
        if (wv[q] > bv || (wv[q] == bv && wi[q] < bi)){ bv = wv[q]; bi = wi[q]; }
      s[bi] = -3e38f;
      tv16[r] = bv; ti16[r] = bi;
      if (r == 15) result = bv;
    }
    __syncthreads();
  }
  float th = result;
  if (t == 0){
    thresholds[p] = th;
    ev_key[p] = 0u;
    lcnt = 16;
    #pragma unroll
    for (int k = 0; k < 16; ++k){
      cand_idx[(size_t)p*CAP + k]   = ti16[k];
      cand_score[(size_t)p*CAP + k] = tv16[k];
    }
  }
  __syncthreads();
  for (int i = t; i < NSAMP; i += 256){
    float x = s[i];
    if (x >= th){
      int pos = atomicAdd(&lcnt, 1);
      if (pos < CAP){
        cand_idx[(size_t)p*CAP + pos]   = i;
        cand_score[(size_t)p*CAP + pos] = x;
      }
    }
  }
  __syncthreads();
  if (t == 0) counters[p] = lcnt < CAP ? lcnt : CAP;
}

// -- bf16-top-64 preselect -> exact rescore -> exact top-50 -> message + slab --
__global__ __launch_bounds__(256) void msg_kernel(
    const int* __restrict__ counters, const int* __restrict__ cand_idx,
    const float* __restrict__ cand_score, const float* __restrict__ memf,
    float* __restrict__ pc, unsigned short* __restrict__ slab,
    const int* __restrict__ active)
{
  if (*active == 0) return;
  __shared__ float sc[CAP]; __shared__ int si[CAP];
  __shared__ __align__(16) float gl[DIM];
  __shared__ int pi_[PRESEL]; __shared__ float exv[PRESEL];
  __shared__ float selv[50]; __shared__ int seli[50]; __shared__ float attn[50];
  __shared__ float wv[4]; __shared__ int wi[4];
  __shared__ float bc;
  int p = blockIdx.x, t = threadIdx.x;
  int n = counters[p]; if (n > CAP) n = CAP;
  #pragma unroll
  for (int j = 0; j < 3; ++j) gl[t + j*256] = pc[(size_t)p*DIM + t + j*256];
  for (int i = t; i < CAP; i += 256){
    sc[i] = (i < n) ? cand_score[(size_t)p*CAP + i] : -3e38f;
    si[i] = (i < n) ? cand_idx[(size_t)p*CAP + i] : 0;
  }
  if (t < PRESEL) exv[t] = -3e38f;
  __syncthreads();
  // phase 1: top-PRESEL by stored bf16 MFMA score
  int NS = n < PRESEL ? n : PRESEL;
  for (int r = 0; r < NS; ++r){
    float v = -3e38f; int idx = 0;
    #pragma unroll
    for (int j = 0; j < 4; ++j){
      int ii = t*4 + j; float x = sc[ii];
      if (x > v){ v = x; idx = ii; }
    }
    for (int off = 32; off > 0; off >>= 1){
      float ov = __shfl_down(v, off, 64); int oi = __shfl_down(idx, off, 64);
      if (ov > v || (ov == v && oi < idx)){ v = ov; idx = oi; }
    }
    if ((t & 63) == 0){ wv[t >> 6] = v; wi[t >> 6] = idx; }
    __syncthreads();
    if (t == 0){
      float bv = wv[0]; int bi = wi[0];
      for (int q = 1; q < 4; ++q)
        if (wv[q] > bv || (wv[q] == bv && wi[q] < bi)){ bv = wv[q]; bi = wi[q]; }
      pi_[r] = si[bi]; sc[bi] = -3e38f;
    }
    __syncthreads();
  }
  // phase 2: exact f32 rescore of preselected rows
  int w = t >> 6, lane = t & 63;
  for (int i = w; i < NS; i += 4){
    const float* row = memf + (size_t)pi_[i]*DIM;
    float s = 0.f;
    #pragma unroll
    for (int j = 0; j < 12; ++j){
      int d = lane + j*64;
      s += row[d] * gl[d];
    }
    for (int off = 32; off > 0; off >>= 1) s += __shfl_down(s, off, 64);
    if (lane == 0) exv[i] = s;
  }
  __syncthreads();
  // phase 3: exact top-50
  int K = NS < 50 ? NS : 50;
  for (int r = 0; r < K; ++r){
    float v = (t < PRESEL) ? exv[t] : -3e38f; int idx = (t < PRESEL) ? t : 0;
    for (int off = 32; off > 0; off >>= 1){
      float ov = __shfl_down(v, off, 64); int oi = __shfl_down(idx, off, 64);
      if (ov > v || (ov == v && oi < idx)){ v = ov; idx = oi; }
    }
    if ((t & 63) == 0){ wv[t >> 6] = v; wi[t >> 6] = idx; }
    __syncthreads();
    if (t == 0){
      float bv = wv[0]; int bi = wi[0];
      for (int q = 1; q < 4; ++q)
        if (wv[q] > bv || (wv[q] == bv && wi[q] < bi)){ bv = wv[q]; bi = wi[q]; }
      selv[r] = bv; seli[r] = pi_[bi]; exv[bi] = -3e38f;
    }
    __syncthreads();
  }
  if (t < K) attn[t] = __expf((selv[t] - selv[0]) * TAUINV);
  __syncthreads();
  if (t == 0){ float s = 0.f; for (int k = 0; k < K; ++k) s += attn[k]; bc = s; }
  __syncthreads();
  float inv = 1.0f / bc;
  int d0 = t, d1 = t + 256, d2 = t + 512;
  float a0 = gl[d0], a1 = gl[d1], a2 = gl[d2];
  for (int k = 0; k < K; ++k){
    float a = attn[k] * inv;
    const float* row = memf + (size_t)seli[k]*DIM;
    a0 += a * row[d0]; a1 += a * row[d1]; a2 += a * row[d2];
  }
  float ss = a0*a0 + a1*a1 + a2*a2;
  for (int off = 32; off > 0; off >>= 1) ss += __shfl_down(ss, off, 64);
  if ((t & 63) == 0) wv[t >> 6] = ss;
  __syncthreads();
  if (t == 0) bc = wv[0] + wv[1] + wv[2] + wv[3];
  __syncthreads();
  float rn = 1.0f / fmaxf(sqrtf(bc), 1e-12f);
  a0 *= rn; a1 *= rn; a2 *= rn;
  float* orow = pc + (size_t)p*DIM;
  orow[d0] = a0; orow[d1] = a1; orow[d2] = a2;
  __syncthreads();
  gl[d0] = a0; gl[d1] = a1; gl[d2] = a2;
  __syncthreads();
  if (t < 96){
    int ks2 = t >> 3, c8 = t & 7;
    const float* sblk = &gl[ks2*64 + c8*8];
    uint4 u = pack8(*(const float4*)sblk, *(const float4*)(sblk + 4));
    *(uint4*)((char*)slab + (((size_t)ks2*NPATCH + p)*128) + ((size_t)(c8 ^ (p & 7))*16)) = u;
  }
}

// ---------------- evidence softmax stats + weighted pooling partials ----------------
__global__ __launch_bounds__(256) void pl2_kernel(
    const unsigned* __restrict__ ev_key, const float* __restrict__ pc,
    float* __restrict__ g_part, const int* __restrict__ active)
{
  if (*active == 0) return;
  __shared__ float wv[4]; __shared__ float bc;
  int t = threadIdx.x;
  float m = -3e38f;
  for (int i = t; i < NPATCH; i += 256) m = fmaxf(m, decf(ev_key[i]));
  for (int off = 32; off > 0; off >>= 1) m = fmaxf(m, __shfl_down(m, off, 64));
  if ((t & 63) == 0) wv[t >> 6] = m;
  __syncthreads();
  if (t == 0) bc = fmaxf(fmaxf(wv[0], wv[1]), fmaxf(wv[2], wv[3]));
  __syncthreads();
  float M = bc;
  __syncthreads();
  float s = 0.f;
  for (int i = t; i < NPATCH; i += 256) s += __expf((decf(ev_key[i]) - M) * TAUINV);
  for (int off = 32; off > 0; off >>= 1) s += __shfl_down(s, off, 64);
  if ((t & 63) == 0) wv[t >> 6] = s;
  __syncthreads();
  if (t == 0) bc = wv[0] + wv[1] + wv[2] + wv[3];
  __syncthreads();
  float invS = 1.0f / bc;
  int pbase = blockIdx.x * 64;
  float a0 = 0.f, a1 = 0.f, a2 = 0.f;
  for (int i = 0; i < 64; ++i){
    int p = pbase + i;
    float wgt = __expf((decf(ev_key[p]) - M) * TAUINV) * invS;
    const float* row = pc + (size_t)p*DIM;
    a0 += wgt * row[t]; a1 += wgt * row[t + 256]; a2 += wgt * row[t + 512];
  }
  g_part[blockIdx.x*DIM + t]       = a0;
  g_part[blockIdx.x*DIM + t + 256] = a1;
  g_part[blockIdx.x*DIM + t + 512] = a2;
}

// ------- logits + entropy + commit (INIT: g=tg; else reduce g_part + norm) -------
template<bool INIT>
__global__ __launch_bounds__(256) void cm_kernel(
    const float* __restrict__ gsrc, const float* __restrict__ protos,
    float* __restrict__ logits_cur, int* __restrict__ step, int* __restrict__ active)
{
  if (!INIT && *active == 0) return;
  __shared__ __align__(16) float gl[DIM];
  __shared__ float lg[NCLS];
  __shared__ float wv[4]; __shared__ float bc;
  int t = threadIdx.x;
  if (INIT){
    #pragma unroll
    for (int j = 0; j < 3; ++j) gl[t + j*256] = gsrc[t + j*256];
  } else {
    float gv[3]; float ss = 0.f;
    #pragma unroll
    for (int j = 0; j < 3; ++j){
      int d = t + j*256;
      float s = 0.f;
      for (int b2 = 0; b2 < 32; ++b2) s += gsrc[b2*DIM + d];
      gv[j] = s; ss += s*s;
    }
    for (int off = 32; off > 0; off >>= 1) ss += __shfl_down(ss, off, 64);
    if ((t & 63) == 0) wv[t >> 6] = ss;
    __syncthreads();
    if (t == 0) bc = wv[0] + wv[1] + wv[2] + wv[3];
    __syncthreads();
    float rn = 1.0f / fmaxf(sqrtf(bc), 1e-12f);
    #pragma unroll
    for (int j = 0; j < 3; ++j) gl[t + j*256] = gv[j] * rn;
  }
  __syncthreads();
  for (int c = t; c < NCLS; c += 256){
    const float4* pr = (const float4*)(protos + (size_t)c*DIM);
    float s = 0.f;
    #pragma unroll 4
    for (int d4 = 0; d4 < DIM/4; ++d4){
      float4 pv = pr[d4];
      float4 gv = *(const float4*)&gl[d4*4];
      s += gv.x*pv.x + gv.y*pv.y + gv.z*pv.z + gv.w*pv.w;
    }
    float L = 100.0f * s;
    lg[c] = L; logits_cur[c] = L;
  }
  __syncthreads();
  float m = -3e38f;
  for (int c = t; c < NCLS; c += 256) m = fmaxf(m, lg[c]);
  for (int off = 32; off > 0; off >>= 1) m = fmaxf(m, __shfl_down(m, off, 64));
  if ((t & 63) == 0) wv[t >> 6] = m;
  __syncthreads();
  if (t == 0) bc = fmaxf(fmaxf(wv[0], wv[1]), fmaxf(wv[2], wv[3]));
  __syncthreads();
  float M = bc;
  __syncthreads();
  float s = 0.f;
  for (int c = t; c < NCLS; c += 256) s += __expf(lg[c] - M);
  for (int off = 32; off > 0; off >>= 1) s += __shfl_down(s, off, 64);
  if ((t & 63) == 0) wv[t >> 6] = s;
  __syncthreads();
  if (t == 0) bc = wv[0] + wv[1] + wv[2] + wv[3];
  __syncthreads();
  float S = bc;
  __syncthreads();
  float hp = 0.f;
  for (int c = t; c < NCLS; c += 256){
    float pcl = __expf(lg[c] - M) / S;
    hp += pcl * __logf(pcl + 1e-10f);
  }
  for (int off = 32; off > 0; off >>= 1) hp += __shfl_down(hp, off, 64);
  if ((t & 63) == 0) wv[t >> 6] = hp;
  __syncthreads();
  if (t == 0){
    float H = -(wv[0] + wv[1] + wv[2] + wv[3]);
    if (INIT){ *step = 0; *active = (H > 0.8f) ? 1 : 0; }
    else     { *step = *step + 1; *active = (H > 0.8f) ? 1 : 0; }
  }
}

// ---------------- publish ----------------
__global__ void pub_kernel(const float* __restrict__ logits_cur, const int* __restrict__ step,
                           float* __restrict__ out)
{
  int i = blockIdx.x*256 + threadIdx.x;
  if (i < NCLS) out[i] = logits_cur[i];
  else if (i == NCLS) out[i] = (float)(*step);
}

extern "C" void kernel_launch(void* const* d_in, const int* in_sizes, int n_in,
                              void* d_out, int out_size, void* d_ws, size_t ws_size,
                              hipStream_t stream)
{
  (void)in_sizes; (void)n_in; (void)out_size; (void)ws_size;
  const float* tg  = (const float*)d_in[0];   // [1,768]
  const float* tp  = (const float*)d_in[1];   // [2048,768]
  const float* mem = (const float*)d_in[2];   // [65536,768]
  const float* anc = (const float*)d_in[3];   // [1000,768]
  const float* cs  = (const float*)d_in[4];   // [1000,768]
  const float* cc  = (const float*)d_in[5];   // [1000]

  char* ws = (char*)d_ws;
  auto al = [](size_t x){ return (x + 255) & ~(size_t)255; };
  size_t OFF_PC   = 0;
  size_t OFF_PROT = al(OFF_PC   + (size_t)NPATCH*DIM*4);
  size_t OFF_ABF  = al(OFF_PROT + (size_t)NCLS*DIM*4);
  size_t OFF_MBF  = al(OFF_ABF  + (size_t)1024*DIM*2);
  size_t OFF_SLAB = al(OFF_MBF  + (size_t)NMEM*DIM*2);
  size_t OFF_SS   = al(OFF_SLAB + (size_t)NPATCH*DIM*2);
  size_t OFF_THR  = al(OFF_SS   + (size_t)NPATCH*NSAMP*4);
  size_t OFF_CNT  = al(OFF_THR  + (size_t)NPATCH*4);
  size_t OFF_CI   = al(OFF_CNT  + (size_t)NPATCH*4);
  size_t OFF_CSC  = al(OFF_CI   + (size_t)NPATCH*CAP*4);
  size_t OFF_EV   = al(OFF_CSC  + (size_t)NPATCH*CAP*4);
  size_t OFF_GP   = al(OFF_EV   + (size_t)NPATCH*4);
  size_t OFF_LC   = al(OFF_GP   + (size_t)32*DIM*4);
  size_t OFF_STEP = al(OFF_LC   + (size_t)NCLS*4);

  float*          pc      = (float*)(ws + OFF_PC);
  float*          protos  = (float*)(ws + OFF_PROT);
  unsigned short* abf     = (unsigned short*)(ws + OFF_ABF);
  unsigned short* mbf     = (unsigned short*)(ws + OFF_MBF);
  unsigned short* slab    = (unsigned short*)(ws + OFF_SLAB);
  float*          simss   = (float*)(ws + OFF_SS);
  float*          thr     = (float*)(ws + OFF_THR);
  int*            cnt     = (int*)(ws + OFF_CNT);
  int*            ci      = (int*)(ws + OFF_CI);
  float*          csc     = (float*)(ws + OFF_CSC);
  unsigned*       evk     = (unsigned*)(ws + OFF_EV);
  float*          gp      = (float*)(ws + OFF_GP);
  float*          lc      = (float*)(ws + OFF_LC);
  int*            stepp   = (int*)(ws + OFF_STEP);
  int*            activep = stepp + 1;

  proto_kernel<<<1024, 256, 0, stream>>>(anc, cs, cc, protos, abf);
  prep_patches<<<(NPATCH*DIM/4)/256, 256, 0, stream>>>(tp, pc);
  conv_kernel<<<(NMEM*12)/256, 256, 0, stream>>>(mem, mbf);
  cm_kernel<true><<<1, 256, 0, stream>>>(tg, protos, lc, stepp, activep);
  slab_kernel<<<NPATCH/2, 192, 0, stream>>>(pc, slab);

  for (int it = 0; it < 3; ++it){
    gemm_kernel<1><<<(NSAMP/128)*16, 256, 0, stream>>>(mbf, slab, simss, evk, activep);
    thresh_kernel<<<NPATCH, 256, 0, stream>>>(simss, thr, cnt, ci, csc, evk, activep);
    gemm256_kernel<<<((NMEM-NSAMP)/256)*8, 512, 0, stream>>>(mbf, NSAMP, slab, thr, cnt, ci, csc, activep);
    msg_kernel<<<NPATCH, 256, 0, stream>>>(cnt, ci, csc, mem, pc, slab, activep);
    gemm_kernel<2><<<(1024/128)*16, 256, 0, stream>>>(abf, slab, simss, evk, activep);
    pl2_kernel<<<32, 256, 0, stream>>>(evk, pc, gp, activep);
    cm_kernel<false><<<1, 256, 0, stream>>>(gp, protos, lc, stepp, activep);
  }
  pub_kernel<<<4, 256, 0, stream>>>(lc, stepp, (float*)d_out);
}

// Round 8
// 2010.495 us; speedup vs baseline: 1.2782x; 1.2782x over previous
//
#include <hip/hip_runtime.h>
#include <hip/hip_bf16.h>
#include <stdint.h>

// ContinuousEpisodicVLM: 3-step episodic retrieval loop.
// bf16 MFMA candidate generation (sampled-threshold filter) + radix-select
// bf16-top-64(+ties) preselect + exact f32 rescore + radix-select exact
// top-50 (node-id tie-break) + softmax message.
// GEMM: proven round-6 structure: 128x128 tile, BK=64, single-buffer 32KB,
// 3 blocks/CU (cross-block overlap is the pipeline), NT=4 M-tiles/block.

typedef __attribute__((ext_vector_type(8))) short short8;
typedef __attribute__((ext_vector_type(4))) float f32x4;

#define DIM    768
#define NPATCH 2048
#define NMEM   65536
#define NCLS   1000
#define NSAMP  4096   // sample = first 4096 rows
#define CAP    1024   // candidate buffer per patch
#define PRESEL 64     // bf16-score preselection rank
#define PCAP   128    // preselection buffer (ties headroom)
#define TAUINV 50.0f  // 1/0.02

__device__ __forceinline__ unsigned short f2bf(float f){
  unsigned b = __float_as_uint(f);
  b += 0x7FFFu + ((b >> 16) & 1u);      // RNE
  return (unsigned short)(b >> 16);
}
__device__ __forceinline__ unsigned encf(float x){
  unsigned b = __float_as_uint(x);
  return (b & 0x80000000u) ? ~b : (b | 0x80000000u);   // order-preserving
}
__device__ __forceinline__ float decf(unsigned k){
  unsigned b = (k & 0x80000000u) ? (k & 0x7FFFFFFFu) : ~k;
  return __uint_as_float(b);
}
__device__ __forceinline__ void gload16(const void* g, void* l){
  __builtin_amdgcn_global_load_lds(
      (const __attribute__((address_space(1))) unsigned int*)g,
      (__attribute__((address_space(3))) unsigned int*)l, 16, 0, 0);
}
__device__ __forceinline__ uint4 pack8(float4 a, float4 b){
  uint4 u;
  u.x = (unsigned)f2bf(a.x) | ((unsigned)f2bf(a.y) << 16);
  u.y = (unsigned)f2bf(a.z) | ((unsigned)f2bf(a.w) << 16);
  u.z = (unsigned)f2bf(b.x) | ((unsigned)f2bf(b.y) << 16);
  u.w = (unsigned)f2bf(b.z) | ((unsigned)f2bf(b.w) << 16);
  return u;
}

// ---- exact k-th largest of keys[0..n) via 4x8-bit radix histogram ----
// hist: shared unsigned[258] (hist[256]=prefix, hist[257]=k-remaining).
// All 256 threads of the block must call. Requires n >= k >= 1.
__device__ __forceinline__ unsigned select_kth(const unsigned* keys, int n, int k,
                                               unsigned* hist, int t)
{
  __syncthreads();
  if (t == 0){ hist[256] = 0u; hist[257] = (unsigned)k; }
  __syncthreads();
  for (int pass = 0; pass < 4; ++pass){
    int shift = 24 - 8*pass;
    hist[t] = 0u;
    __syncthreads();
    unsigned pref = hist[256];
    for (int i = t; i < n; i += 256){
      unsigned key = keys[i];
      bool ok = (pass == 0) || ((key >> (shift + 8)) == pref);
      if (ok) atomicAdd(&hist[(key >> shift) & 255u], 1u);
    }
    __syncthreads();
    if (t == 0){
      unsigned krem = hist[257];
      unsigned cum = 0u; int b = 255;
      for (; b >= 0; --b){ cum += hist[b]; if (cum >= krem) break; }
      if (b < 0) b = 0;
      unsigned above = cum - hist[b];       // strictly above bin b
      hist[257] = krem - above;
      hist[256] = (pref << 8) | (unsigned)b;
    }
    __syncthreads();
  }
  return hist[256];
}

// ---------------- protos + anchors_bf16 (pre-swizzled) ----------------
__global__ __launch_bounds__(256) void proto_kernel(
    const float* __restrict__ anchors, const float* __restrict__ sums,
    const float* __restrict__ counts, float* __restrict__ protos,
    unsigned short* __restrict__ anchors_bf)
{
  int c = blockIdx.x, t = threadIdx.x;
  if (c >= NCLS){  // pad rows 1000..1023 with zeros
    for (int j = 0; j < 3; ++j) anchors_bf[(size_t)c*DIM + t + j*256] = 0;
    return;
  }
  __shared__ float wv[4]; __shared__ float bc;
  float cnt = fmaxf(counts[c], 1.0f);
  float v[3];
  #pragma unroll
  for (int j = 0; j < 3; ++j) v[j] = sums[(size_t)c*DIM + t + j*256] / cnt;
  float ss = v[0]*v[0] + v[1]*v[1] + v[2]*v[2];
  for (int off = 32; off > 0; off >>= 1) ss += __shfl_down(ss, off, 64);
  if ((t & 63) == 0) wv[t >> 6] = ss;
  __syncthreads();
  if (t == 0) bc = wv[0] + wv[1] + wv[2] + wv[3];
  __syncthreads();
  float rn = 1.0f / fmaxf(sqrtf(bc), 1e-12f);
  __syncthreads();
  float pr[3];
  #pragma unroll
  for (int j = 0; j < 3; ++j){
    int d = t + j*256;
    float a = anchors[(size_t)c*DIM + d];
    pr[j] = a + v[j] * rn;                         // ALPHA = 1.0
    int dd = (d & ~63) | ((((d >> 3) ^ c) & 7) << 3) | (d & 7);
    anchors_bf[(size_t)c*DIM + dd] = f2bf(a);
  }
  ss = pr[0]*pr[0] + pr[1]*pr[1] + pr[2]*pr[2];
  for (int off = 32; off > 0; off >>= 1) ss += __shfl_down(ss, off, 64);
  if ((t & 63) == 0) wv[t >> 6] = ss;
  __syncthreads();
  if (t == 0) bc = wv[0] + wv[1] + wv[2] + wv[3];
  __syncthreads();
  float rn2 = 1.0f / fmaxf(sqrtf(bc), 1e-12f);
  #pragma unroll
  for (int j = 0; j < 3; ++j) protos[(size_t)c*DIM + t + j*256] = pr[j] * rn2;
}

// ---------------- patches f32 working copy ----------------
__global__ __launch_bounds__(256) void prep_patches(
    const float* __restrict__ tp, float* __restrict__ pc)
{
  size_t i = (size_t)blockIdx.x*256 + threadIdx.x;
  *(float4*)(pc + i*4) = *(const float4*)(tp + i*4);
}

// ---------------- f32 -> bf16 pre-swizzled conversion ----------------
__global__ __launch_bounds__(256) void conv_kernel(
    const float* __restrict__ src, unsigned short* __restrict__ dst)
{
  int id = blockIdx.x*256 + threadIdx.x;   // one per 64-elem block
  int row = id / 12, blk = id % 12;
  const float4* s = (const float4*)(src + (size_t)row*DIM + blk*64);
  unsigned short* drow = dst + (size_t)row*DIM + blk*64;
  int key = row & 7;
  #pragma unroll
  for (int c8 = 0; c8 < 8; ++c8){
    uint4 u = pack8(s[c8*2], s[c8*2+1]);
    *(uint4*)(drow + (c8 ^ key)*8) = u;
  }
}

// ---------------- initial K-major swizzled patch slab [12][2048][64] ----------------
__global__ __launch_bounds__(192) void slab_kernel(
    const float* __restrict__ pc, unsigned short* __restrict__ slab)
{
  int b = blockIdx.x, t = threadIdx.x;
  int p = b*2 + (t >= 96 ? 1 : 0);
  int q = (t >= 96) ? t - 96 : t;
  int ks = q >> 3, c8 = q & 7;
  const float* s = pc + (size_t)p*DIM + ks*64 + c8*8;
  uint4 u = pack8(*(const float4*)s, *(const float4*)(s + 4));
  *(uint4*)((char*)slab + (((size_t)ks*NPATCH + p)*128) + ((size_t)(c8 ^ (p & 7))*16)) = u;
}

// ---------------- unified MFMA GEMM (single-buffer, NT tiles/block) ----------------
// MODE 0: A=mbf rows rowbase.., filter >= th, append idx+score
// MODE 1: A=mbf rows 0..4095, write sims_sample[patch][node]
// MODE 2: A=anchors_bf (rows>=1000 zero), atomicMax evidence
template<int MODE, int NT>
__global__ __launch_bounds__(256, 3) void gemm_kernel(
    const unsigned short* __restrict__ Abf, int rowbase,
    const unsigned short* __restrict__ Bslab,
    const float* __restrict__ thresholds,
    int* __restrict__ counters,
    int* __restrict__ cand_idx,
    float* __restrict__ cand_score,
    float* __restrict__ sims_sample,
    unsigned* __restrict__ ev_key,
    const int* __restrict__ active)
{
  if (*active == 0) return;
  __shared__ __align__(16) unsigned short Al[128*64];
  __shared__ __align__(16) unsigned short Bl[128*64];
  int b = blockIdx.x, nwg = gridDim.x;
  int wg = (b & 7)*(nwg >> 3) + (b >> 3);   // XCD-chunked swizzle (nwg%8==0)
  int mt0 = (wg >> 4) * NT, pt = wg & 15;
  int t = threadIdx.x, w = t >> 6, lane = t & 63, l15 = lane & 15, l4 = lane >> 4;
  int wr = w >> 1, wc = w & 1;
  int pbase = pt*128;
  int srow = w*8 + (lane >> 3);
  int scol = (lane & 7)*16;

  const char* Ab = (const char*)Abf;
  const char* Bb = (const char*)Bslab;

  float thv[4];
  if (MODE == 0){
    #pragma unroll
    for (int g = 0; g < 4; ++g) thv[g] = thresholds[pbase + wc*64 + g*16 + l15];
  }

  f32x4 acc[4][4];
  #pragma unroll
  for (int x = 0; x < 4; ++x)
    #pragma unroll
    for (int y = 0; y < 4; ++y) acc[x][y] = (f32x4){0.f, 0.f, 0.f, 0.f};

  const int NSTEP = NT * 12;
  for (int s = 0; s < NSTEP; ++s){
    int tile = s / 12, ks = s % 12;
    if (s) __syncthreads();                 // prev ds_reads done before overwrite
    size_t arow0 = (size_t)rowbase + ((size_t)(mt0 + tile))*128;
    #pragma unroll
    for (int i = 0; i < 4; ++i){
      const void* ga = Ab + ((arow0 + srow + i*32)*(size_t)(DIM*2)) + ks*128 + scol;
      gload16(ga, (char*)Al + i*4096 + w*1024);
      const void* gb = Bb + (((size_t)ks*NPATCH + pbase)*128) + i*4096 + w*1024 + lane*16;
      gload16(gb, (char*)Bl + i*4096 + w*1024);
    }
    __syncthreads();                        // compiler drains vmcnt before barrier

    short8 af[2][4], bf_[2][4];
    #pragma unroll
    for (int kk = 0; kk < 2; ++kk){
      #pragma unroll
      for (int ng = 0; ng < 4; ++ng){
        int row = wr*64 + ng*16 + l15;
        int slot = (kk*4 + l4) ^ (row & 7);
        af[kk][ng] = *(const short8*)((const char*)Al + row*128 + slot*16);
      }
      #pragma unroll
      for (int g = 0; g < 4; ++g){
        int row = wc*64 + g*16 + l15;
        int slot = (kk*4 + l4) ^ (row & 7);
        bf_[kk][g] = *(const short8*)((const char*)Bl + row*128 + slot*16);
      }
    }
    #pragma unroll
    for (int kk = 0; kk < 2; ++kk)
      #pragma unroll
      for (int ng = 0; ng < 4; ++ng)
        #pragma unroll
        for (int g = 0; g < 4; ++g)
          acc[ng][g] = __builtin_amdgcn_mfma_f32_16x16x32_bf16(af[kk][ng], bf_[kk][g], acc[ng][g], 0, 0, 0);

    if (ks == 11){
      int nodebase = rowbase + (mt0 + tile)*128 + wr*64;
      if (MODE == 0){
        #pragma unroll
        for (int g = 0; g < 4; ++g){
          int patch = pbase + wc*64 + g*16 + l15;
          float th = thv[g];
          #pragma unroll
          for (int ng = 0; ng < 4; ++ng){
            #pragma unroll
            for (int i = 0; i < 4; ++i){
              float v = acc[ng][g][i];
              if (v >= th){
                int node = nodebase + ng*16 + l4*4 + i;
                int pos = atomicAdd(&counters[patch], 1);
                if (pos < CAP){
                  cand_idx[(size_t)patch*CAP + pos]   = node;
                  cand_score[(size_t)patch*CAP + pos] = v;
                }
              }
            }
          }
        }
      } else if (MODE == 1){
        #pragma unroll
        for (int g = 0; g < 4; ++g){
          int patch = pbase + wc*64 + g*16 + l15;
          #pragma unroll
          for (int ng = 0; ng < 4; ++ng){
            int col = nodebase + ng*16 + l4*4;
            *(f32x4*)(sims_sample + (size_t)patch*NSAMP + col) = acc[ng][g];
          }
        }
      } else {
        #pragma unroll
        for (int g = 0; g < 4; ++g){
          int patch = pbase + wc*64 + g*16 + l15;
          float m = -3e38f; bool any = false;
          #pragma unroll
          for (int ng = 0; ng < 4; ++ng){
            #pragma unroll
            for (int i = 0; i < 4; ++i){
              int a = nodebase + ng*16 + l4*4 + i;
              if (a < NCLS){ m = fmaxf(m, acc[ng][g][i]); any = true; }
            }
          }
          if (any) atomicMax(&ev_key[patch], encf(m));
        }
      }
      if (tile + 1 < NT){
        #pragma unroll
        for (int x = 0; x < 4; ++x)
          #pragma unroll
          for (int y = 0; y < 4; ++y) acc[x][y] = (f32x4){0.f, 0.f, 0.f, 0.f};
      }
    }
  }
}

// -- threshold = 16th max of sampled sims (radix select); append all >= th --
__global__ __launch_bounds__(256) void thresh_kernel(
    const float* __restrict__ sims, float* __restrict__ thresholds,
    int* __restrict__ counters, int* __restrict__ cand_idx,
    float* __restrict__ cand_score, unsigned* __restrict__ ev_key,
    const int* __restrict__ active)
{
  if (*active == 0) return;
  __shared__ unsigned keys[NSAMP];
  __shared__ unsigned hist[258];
  __shared__ int lcnt;
  int p = blockIdx.x, t = threadIdx.x;
  const float4* src = (const float4*)(sims + (size_t)p*NSAMP);
  for (int i = t; i < NSAMP/4; i += 256){
    float4 v = src[i];
    keys[i*4+0] = encf(v.x); keys[i*4+1] = encf(v.y);
    keys[i*4+2] = encf(v.z); keys[i*4+3] = encf(v.w);
  }
  unsigned kth = select_kth(keys, NSAMP, 16, hist, t);   // entry sync covers writes
  if (t == 0){ thresholds[p] = decf(kth); ev_key[p] = 0u; lcnt = 0; }
  __syncthreads();
  for (int i = t; i < NSAMP; i += 256){
    unsigned key = keys[i];
    if (key >= kth){
      int pos = atomicAdd(&lcnt, 1);
      if (pos < CAP){
        cand_idx[(size_t)p*CAP + pos]   = i;
        cand_score[(size_t)p*CAP + pos] = decf(key);
      }
    }
  }
  __syncthreads();
  if (t == 0) counters[p] = lcnt < CAP ? lcnt : CAP;
}

// -- radix preselect (bf16 top-64 incl. ties) -> exact rescore -> radix exact
//    top-50 (node-id tie-break) -> softmax message + slab update --
__global__ __launch_bounds__(256) void msg_kernel(
    const int* __restrict__ counters, const int* __restrict__ cand_idx,
    const float* __restrict__ cand_score, const float* __restrict__ memf,
    float* __restrict__ pc, unsigned short* __restrict__ slab,
    const int* __restrict__ active)
{
  if (*active == 0) return;
  __shared__ unsigned sk[CAP]; __shared__ int si[CAP];
  __shared__ __align__(16) float gl[DIM];
  __shared__ unsigned hist[258];
  __shared__ int pn[PCAP]; __shared__ float pv[PCAP];
  __shared__ float selv[64]; __shared__ int seli[64]; __shared__ float attn[64];
  __shared__ float wv[4]; __shared__ float bc;
  __shared__ int cnt2;
  int p = blockIdx.x, t = threadIdx.x;
  int n = counters[p]; if (n > CAP) n = CAP;
  #pragma unroll
  for (int j = 0; j < 3; ++j) gl[t + j*256] = pc[(size_t)p*DIM + t + j*256];
  for (int i = t; i < CAP; i += 256){
    sk[i] = (i < n) ? encf(cand_score[(size_t)p*CAP + i]) : 0u;  // 0 < any real
    si[i] = (i < n) ? cand_idx[(size_t)p*CAP + i] : 0;
  }
  // ---- preselect: all with bf16 score >= 64th-largest (superset w/ ties) ----
  unsigned kth64 = 1u;
  if (n > PRESEL) kth64 = select_kth(sk, n, PRESEL, hist, t);
  else            __syncthreads();
  if (t == 0) cnt2 = 0;
  __syncthreads();
  for (int i = t; i < n; i += 256){
    if (sk[i] >= kth64){
      int pos = atomicAdd(&cnt2, 1);
      if (pos < PCAP) pn[pos] = si[i];
    }
  }
  __syncthreads();
  int m = cnt2 < PCAP ? cnt2 : PCAP;
  // ---- exact f32 rescore of preselected rows ----
  int w = t >> 6, lane = t & 63;
  for (int i = w; i < m; i += 4){
    const float* row = memf + (size_t)pn[i]*DIM;
    float s = 0.f;
    #pragma unroll
    for (int j = 0; j < 12; ++j){
      int d = lane + j*64;
      s += row[d] * gl[d];
    }
    for (int off = 32; off > 0; off >>= 1) s += __shfl_down(s, off, 64);
    if (lane == 0) pv[i] = s;
  }
  __syncthreads();
  int K = m < 50 ? m : 50;
  if (t < m) sk[t] = encf(pv[t]);          // exact keys (m <= 128 < 256)
  unsigned kth50 = 1u;
  if (m > K) kth50 = select_kth(sk, m, K, hist, t);   // entry sync covers sk
  else       __syncthreads();
  if (t == 0) cnt2 = 0;
  __syncthreads();
  if (t < m && sk[t] > kth50){             // strictly-greater: all selected
    int pos = atomicAdd(&cnt2, 1);
    seli[pos] = pn[t]; selv[pos] = pv[t];
    sk[t] = 0u;
  }
  __syncthreads();
  if (t == 0){                             // boundary ties: smallest node id first
    int c = cnt2;
    for (int j = c; j < K; ++j){
      int best = -1, bestnode = 0x7FFFFFFF;
      for (int i = 0; i < m; ++i)
        if (sk[i] == kth50 && pn[i] < bestnode){ best = i; bestnode = pn[i]; }
      if (best < 0) break;
      seli[j] = pn[best]; selv[j] = pv[best]; sk[best] = 0u;
    }
  }
  __syncthreads();
  // ---- vmax + softmax weights ----
  float v = (t < K) ? selv[t] : -3e38f;
  for (int off = 32; off > 0; off >>= 1) v = fmaxf(v, __shfl_down(v, off, 64));
  if ((t & 63) == 0) wv[t >> 6] = v;
  __syncthreads();
  if (t == 0) bc = fmaxf(fmaxf(wv[0], wv[1]), fmaxf(wv[2], wv[3]));
  __syncthreads();
  float vmax = bc;
  __syncthreads();
  if (t < K) attn[t] = __expf((selv[t] - vmax) * TAUINV);
  __syncthreads();
  if (t == 0){ float s = 0.f; for (int k = 0; k < K; ++k) s += attn[k]; bc = s; }
  __syncthreads();
  float inv = 1.0f / bc;
  // ---- weighted message + renorm ----
  int d0 = t, d1 = t + 256, d2 = t + 512;
  float a0 = gl[d0], a1 = gl[d1], a2 = gl[d2];
  for (int k = 0; k < K; ++k){
    float a = attn[k] * inv;
    const float* row = memf + (size_t)seli[k]*DIM;
    a0 += a * row[d0]; a1 += a * row[d1]; a2 += a * row[d2];
  }
  float ss = a0*a0 + a1*a1 + a2*a2;
  for (int off = 32; off > 0; off >>= 1) ss += __shfl_down(ss, off, 64);
  if ((t & 63) == 0) wv[t >> 6] = ss;
  __syncthreads();
  if (t == 0) bc = wv[0] + wv[1] + wv[2] + wv[3];
  __syncthreads();
  float rn = 1.0f / fmaxf(sqrtf(bc), 1e-12f);
  a0 *= rn; a1 *= rn; a2 *= rn;
  float* orow = pc + (size_t)p*DIM;
  orow[d0] = a0; orow[d1] = a1; orow[d2] = a2;
  __syncthreads();
  gl[d0] = a0; gl[d1] = a1; gl[d2] = a2;
  __syncthreads();
  if (t < 96){
    int ks2 = t >> 3, c8 = t & 7;
    const float* sblk = &gl[ks2*64 + c8*8];
    uint4 u = pack8(*(const float4*)sblk, *(const float4*)(sblk + 4));
    *(uint4*)((char*)slab + (((size_t)ks2*NPATCH + p)*128) + ((size_t)(c8 ^ (p & 7))*16)) = u;
  }
}

// ---------------- evidence softmax stats + weighted pooling partials ----------------
__global__ __launch_bounds__(256) void pl2_kernel(
    const unsigned* __restrict__ ev_key, const float* __restrict__ pc,
    float* __restrict__ g_part, const int* __restrict__ active)
{
  if (*active == 0) return;
  __shared__ float wv[4]; __shared__ float bc;
  int t = threadIdx.x;
  float m = -3e38f;
  for (int i = t; i < NPATCH; i += 256) m = fmaxf(m, decf(ev_key[i]));
  for (int off = 32; off > 0; off >>= 1) m = fmaxf(m, __shfl_down(m, off, 64));
  if ((t & 63) == 0) wv[t >> 6] = m;
  __syncthreads();
  if (t == 0) bc = fmaxf(fmaxf(wv[0], wv[1]), fmaxf(wv[2], wv[3]));
  __syncthreads();
  float M = bc;
  __syncthreads();
  float s = 0.f;
  for (int i = t; i < NPATCH; i += 256) s += __expf((decf(ev_key[i]) - M) * TAUINV);
  for (int off = 32; off > 0; off >>= 1) s += __shfl_down(s, off, 64);
  if ((t & 63) == 0) wv[t >> 6] = s;
  __syncthreads();
  if (t == 0) bc = wv[0] + wv[1] + wv[2] + wv[3];
  __syncthreads();
  float invS = 1.0f / bc;
  int pbase = blockIdx.x * 64;
  float a0 = 0.f, a1 = 0.f, a2 = 0.f;
  for (int i = 0; i < 64; ++i){
    int p = pbase + i;
    float wgt = __expf((decf(ev_key[p]) - M) * TAUINV) * invS;
    const float* row = pc + (size_t)p*DIM;
    a0 += wgt * row[t]; a1 += wgt * row[t + 256]; a2 += wgt * row[t + 512];
  }
  g_part[blockIdx.x*DIM + t]       = a0;
  g_part[blockIdx.x*DIM + t + 256] = a1;
  g_part[blockIdx.x*DIM + t + 512] = a2;
}

// ------- logits + entropy + commit (INIT: g=tg; else reduce g_part + norm) -------
template<bool INIT>
__global__ __launch_bounds__(256) void cm_kernel(
    const float* __restrict__ gsrc, const float* __restrict__ protos,
    float* __restrict__ logits_cur, int* __restrict__ step, int* __restrict__ active)
{
  if (!INIT && *active == 0) return;
  __shared__ __align__(16) float gl[DIM];
  __shared__ float lg[NCLS];
  __shared__ float wv[4]; __shared__ float bc;
  int t = threadIdx.x;
  if (INIT){
    #pragma unroll
    for (int j = 0; j < 3; ++j) gl[t + j*256] = gsrc[t + j*256];
  } else {
    float gv[3]; float ss = 0.f;
    #pragma unroll
    for (int j = 0; j < 3; ++j){
      int d = t + j*256;
      float s = 0.f;
      for (int b2 = 0; b2 < 32; ++b2) s += gsrc[b2*DIM + d];
      gv[j] = s; ss += s*s;
    }
    for (int off = 32; off > 0; off >>= 1) ss += __shfl_down(ss, off, 64);
    if ((t & 63) == 0) wv[t >> 6] = ss;
    __syncthreads();
    if (t == 0) bc = wv[0] + wv[1] + wv[2] + wv[3];
    __syncthreads();
    float rn = 1.0f / fmaxf(sqrtf(bc), 1e-12f);
    #pragma unroll
    for (int j = 0; j < 3; ++j) gl[t + j*256] = gv[j] * rn;
  }
  __syncthreads();
  for (int c = t; c < NCLS; c += 256){
    const float4* pr = (const float4*)(protos + (size_t)c*DIM);
    float s = 0.f;
    #pragma unroll 4
    for (int d4 = 0; d4 < DIM/4; ++d4){
      float4 pv = pr[d4];
      float4 gv = *(const float4*)&gl[d4*4];
      s += gv.x*pv.x + gv.y*pv.y + gv.z*pv.z + gv.w*pv.w;
    }
    float L = 100.0f * s;
    lg[c] = L; logits_cur[c] = L;
  }
  __syncthreads();
  float m = -3e38f;
  for (int c = t; c < NCLS; c += 256) m = fmaxf(m, lg[c]);
  for (int off = 32; off > 0; off >>= 1) m = fmaxf(m, __shfl_down(m, off, 64));
  if ((t & 63) == 0) wv[t >> 6] = m;
  __syncthreads();
  if (t == 0) bc = fmaxf(fmaxf(wv[0], wv[1]), fmaxf(wv[2], wv[3]));
  __syncthreads();
  float M = bc;
  __syncthreads();
  float s = 0.f;
  for (int c = t; c < NCLS; c += 256) s += __expf(lg[c] - M);
  for (int off = 32; off > 0; off >>= 1) s += __shfl_down(s, off, 64);
  if ((t & 63) == 0) wv[t >> 6] = s;
  __syncthreads();
  if (t == 0) bc = wv[0] + wv[1] + wv[2] + wv[3];
  __syncthreads();
  float S = bc;
  __syncthreads();
  float hp = 0.f;
  for (int c = t; c < NCLS; c += 256){
    float pcl = __expf(lg[c] - M) / S;
    hp += pcl * __logf(pcl + 1e-10f);
  }
  for (int off = 32; off > 0; off >>= 1) hp += __shfl_down(hp, off, 64);
  if ((t & 63) == 0) wv[t >> 6] = hp;
  __syncthreads();
  if (t == 0){
    float H = -(wv[0] + wv[1] + wv[2] + wv[3]);
    if (INIT){ *step = 0; *active = (H > 0.8f) ? 1 : 0; }
    else     { *step = *step + 1; *active = (H > 0.8f) ? 1 : 0; }
  }
}

// ---------------- publish ----------------
__global__ void pub_kernel(const float* __restrict__ logits_cur, const int* __restrict__ step,
                           float* __restrict__ out)
{
  int i = blockIdx.x*256 + threadIdx.x;
  if (i < NCLS) out[i] = logits_cur[i];
  else if (i == NCLS) out[i] = (float)(*step);
}

extern "C" void kernel_launch(void* const* d_in, const int* in_sizes, int n_in,
                              void* d_out, int out_size, void* d_ws, size_t ws_size,
                              hipStream_t stream)
{
  (void)in_sizes; (void)n_in; (void)out_size; (void)ws_size;
  const float* tg  = (const float*)d_in[0];   // [1,768]
  const float* tp  = (const float*)d_in[1];   // [2048,768]
  const float* mem = (const float*)d_in[2];   // [65536,768]
  const float* anc = (const float*)d_in[3];   // [1000,768]
  const float* cs  = (const float*)d_in[4];   // [1000,768]
  const float* cc  = (const float*)d_in[5];   // [1000]

  char* ws = (char*)d_ws;
  auto al = [](size_t x){ return (x + 255) & ~(size_t)255; };
  size_t OFF_PC   = 0;
  size_t OFF_PROT = al(OFF_PC   + (size_t)NPATCH*DIM*4);
  size_t OFF_ABF  = al(OFF_PROT + (size_t)NCLS*DIM*4);
  size_t OFF_MBF  = al(OFF_ABF  + (size_t)1024*DIM*2);
  size_t OFF_SLAB = al(OFF_MBF  + (size_t)NMEM*DIM*2);
  size_t OFF_SS   = al(OFF_SLAB + (size_t)NPATCH*DIM*2);
  size_t OFF_THR  = al(OFF_SS   + (size_t)NPATCH*NSAMP*4);
  size_t OFF_CNT  = al(OFF_THR  + (size_t)NPATCH*4);
  size_t OFF_CI   = al(OFF_CNT  + (size_t)NPATCH*4);
  size_t OFF_CSC  = al(OFF_CI   + (size_t)NPATCH*CAP*4);
  size_t OFF_EV   = al(OFF_CSC  + (size_t)NPATCH*CAP*4);
  size_t OFF_GP   = al(OFF_EV   + (size_t)NPATCH*4);
  size_t OFF_LC   = al(OFF_GP   + (size_t)32*DIM*4);
  size_t OFF_STEP = al(OFF_LC   + (size_t)NCLS*4);

  float*          pc      = (float*)(ws + OFF_PC);
  float*          protos  = (float*)(ws + OFF_PROT);
  unsigned short* abf     = (unsigned short*)(ws + OFF_ABF);
  unsigned short* mbf     = (unsigned short*)(ws + OFF_MBF);
  unsigned short* slab    = (unsigned short*)(ws + OFF_SLAB);
  float*          simss   = (float*)(ws + OFF_SS);
  float*          thr     = (float*)(ws + OFF_THR);
  int*            cnt     = (int*)(ws + OFF_CNT);
  int*            ci      = (int*)(ws + OFF_CI);
  float*          csc     = (float*)(ws + OFF_CSC);
  unsigned*       evk     = (unsigned*)(ws + OFF_EV);
  float*          gp      = (float*)(ws + OFF_GP);
  float*          lc      = (float*)(ws + OFF_LC);
  int*            stepp   = (int*)(ws + OFF_STEP);
  int*            activep = stepp + 1;

  proto_kernel<<<1024, 256, 0, stream>>>(anc, cs, cc, protos, abf);
  prep_patches<<<(NPATCH*DIM/4)/256, 256, 0, stream>>>(tp, pc);
  conv_kernel<<<(NMEM*12)/256, 256, 0, stream>>>(mem, mbf);
  cm_kernel<true><<<1, 256, 0, stream>>>(tg, protos, lc, stepp, activep);
  slab_kernel<<<NPATCH/2, 192, 0, stream>>>(pc, slab);

  for (int it = 0; it < 3; ++it){
    gemm_kernel<1,1><<<(NSAMP/128)*16, 256, 0, stream>>>(mbf, 0, slab, thr, cnt, ci, csc, simss, evk, activep);
    thresh_kernel<<<NPATCH, 256, 0, stream>>>(simss, thr, cnt, ci, csc, evk, activep);
    gemm_kernel<0,4><<<((NMEM-NSAMP)/512)*16, 256, 0, stream>>>(mbf, NSAMP, slab, thr, cnt, ci, csc, simss, evk, activep);
    msg_kernel<<<NPATCH, 256, 0, stream>>>(cnt, ci, csc, mem, pc, slab, activep);
    gemm_kernel<2,1><<<(1024/128)*16, 256, 0, stream>>>(abf, 0, slab, thr, cnt, ci, csc, simss, evk, activep);
    pl2_kernel<<<32, 256, 0, stream>>>(evk, pc, gp, activep);
    cm_kernel<false><<<1, 256, 0, stream>>>(gp, protos, lc, stepp, activep);
  }
  pub_kernel<<<4, 256, 0, stream>>>(lc, stepp, (float*)d_out);
}

// Round 9
// 1760.421 us; speedup vs baseline: 1.4597x; 1.1421x over previous
//
#include <hip/hip_runtime.h>
#include <hip/hip_bf16.h>
#include <stdint.h>

// ContinuousEpisodicVLM: 3-step episodic retrieval loop.
// i8 MFMA candidate generation (2x bf16 rate; per-row scales) + radix-select
// bf16-top-64(+ties) preselect + exact f32 rescore + radix exact top-50 +
// softmax message. Evidence GEMM stays bf16 (error-chain isolation).
// GEMM structure: 128x128 tile, BK=64, single-buffer LDS, 3 blocks/CU
// (cross-block overlap is the pipeline), NT=4 M-tiles/block.

typedef __attribute__((ext_vector_type(8))) short short8;
typedef __attribute__((ext_vector_type(4))) float f32x4;
typedef __attribute__((ext_vector_type(4))) int   i32x4;

#define DIM    768
#define NPATCH 2048
#define NMEM   65536
#define NCLS   1000
#define NSAMP  4096   // sample = first 4096 rows
#define CAP    1024   // candidate buffer per patch
#define PRESEL 64     // preselection rank
#define PCAP   128    // preselection buffer (ties headroom)
#define TAUINV 50.0f  // 1/0.02

__device__ __forceinline__ unsigned short f2bf(float f){
  unsigned b = __float_as_uint(f);
  b += 0x7FFFu + ((b >> 16) & 1u);      // RNE
  return (unsigned short)(b >> 16);
}
__device__ __forceinline__ unsigned encf(float x){
  unsigned b = __float_as_uint(x);
  return (b & 0x80000000u) ? ~b : (b | 0x80000000u);   // order-preserving
}
__device__ __forceinline__ float decf(unsigned k){
  unsigned b = (k & 0x80000000u) ? (k & 0x7FFFFFFFu) : ~k;
  return __uint_as_float(b);
}
__device__ __forceinline__ void gload16(const void* g, void* l){
  __builtin_amdgcn_global_load_lds(
      (const __attribute__((address_space(1))) unsigned int*)g,
      (__attribute__((address_space(3))) unsigned int*)l, 16, 0, 0);
}
__device__ __forceinline__ uint4 pack8(float4 a, float4 b){
  uint4 u;
  u.x = (unsigned)f2bf(a.x) | ((unsigned)f2bf(a.y) << 16);
  u.y = (unsigned)f2bf(a.z) | ((unsigned)f2bf(a.w) << 16);
  u.z = (unsigned)f2bf(b.x) | ((unsigned)f2bf(b.y) << 16);
  u.w = (unsigned)f2bf(b.z) | ((unsigned)f2bf(b.w) << 16);
  return u;
}
__device__ __forceinline__ uint4 packq16(const float* s, float inv){
  unsigned wd[4];
  #pragma unroll
  for (int k = 0; k < 4; ++k){
    unsigned v = 0;
    #pragma unroll
    for (int j = 0; j < 4; ++j){
      int q = __float2int_rn(s[k*4 + j] * inv);
      q = q > 127 ? 127 : (q < -127 ? -127 : q);
      v |= ((unsigned)(q & 255)) << (8*j);
    }
    wd[k] = v;
  }
  return make_uint4(wd[0], wd[1], wd[2], wd[3]);
}

// ---- exact k-th largest of keys[0..n) via 4x8-bit radix histogram ----
__device__ __forceinline__ unsigned select_kth(const unsigned* keys, int n, int k,
                                               unsigned* hist, int t)
{
  __syncthreads();
  if (t == 0){ hist[256] = 0u; hist[257] = (unsigned)k; }
  __syncthreads();
  for (int pass = 0; pass < 4; ++pass){
    int shift = 24 - 8*pass;
    hist[t] = 0u;
    __syncthreads();
    unsigned pref = hist[256];
    for (int i = t; i < n; i += 256){
      unsigned key = keys[i];
      bool ok = (pass == 0) || ((key >> (shift + 8)) == pref);
      if (ok) atomicAdd(&hist[(key >> shift) & 255u], 1u);
    }
    __syncthreads();
    if (t == 0){
      unsigned krem = hist[257];
      unsigned cum = 0u; int b = 255;
      for (; b >= 0; --b){ cum += hist[b]; if (cum >= krem) break; }
      if (b < 0) b = 0;
      unsigned above = cum - hist[b];
      hist[257] = krem - above;
      hist[256] = (pref << 8) | (unsigned)b;
    }
    __syncthreads();
  }
  return hist[256];
}

// ---------------- protos + anchors_bf16 (pre-swizzled, 128B-row XOR) ----------------
__global__ __launch_bounds__(256) void proto_kernel(
    const float* __restrict__ anchors, const float* __restrict__ sums,
    const float* __restrict__ counts, float* __restrict__ protos,
    unsigned short* __restrict__ anchors_bf)
{
  int c = blockIdx.x, t = threadIdx.x;
  if (c >= NCLS){
    for (int j = 0; j < 3; ++j) anchors_bf[(size_t)c*DIM + t + j*256] = 0;
    return;
  }
  __shared__ float wv[4]; __shared__ float bc;
  float cnt = fmaxf(counts[c], 1.0f);
  float v[3];
  #pragma unroll
  for (int j = 0; j < 3; ++j) v[j] = sums[(size_t)c*DIM + t + j*256] / cnt;
  float ss = v[0]*v[0] + v[1]*v[1] + v[2]*v[2];
  for (int off = 32; off > 0; off >>= 1) ss += __shfl_down(ss, off, 64);
  if ((t & 63) == 0) wv[t >> 6] = ss;
  __syncthreads();
  if (t == 0) bc = wv[0] + wv[1] + wv[2] + wv[3];
  __syncthreads();
  float rn = 1.0f / fmaxf(sqrtf(bc), 1e-12f);
  __syncthreads();
  float pr[3];
  #pragma unroll
  for (int j = 0; j < 3; ++j){
    int d = t + j*256;
    float a = anchors[(size_t)c*DIM + d];
    pr[j] = a + v[j] * rn;                         // ALPHA = 1.0
    int dd = (d & ~63) | ((((d >> 3) ^ c) & 7) << 3) | (d & 7);
    anchors_bf[(size_t)c*DIM + dd] = f2bf(a);
  }
  ss = pr[0]*pr[0] + pr[1]*pr[1] + pr[2]*pr[2];
  for (int off = 32; off > 0; off >>= 1) ss += __shfl_down(ss, off, 64);
  if ((t & 63) == 0) wv[t >> 6] = ss;
  __syncthreads();
  if (t == 0) bc = wv[0] + wv[1] + wv[2] + wv[3];
  __syncthreads();
  float rn2 = 1.0f / fmaxf(sqrtf(bc), 1e-12f);
  #pragma unroll
  for (int j = 0; j < 3; ++j) protos[(size_t)c*DIM + t + j*256] = pr[j] * rn2;
}

// ---------------- patches f32 working copy ----------------
__global__ __launch_bounds__(256) void prep_patches(
    const float* __restrict__ tp, float* __restrict__ pc)
{
  size_t i = (size_t)blockIdx.x*256 + threadIdx.x;
  *(float4*)(pc + i*4) = *(const float4*)(tp + i*4);
}

// ------- memory f32 -> per-row-scaled i8 (chunk-swizzled 64B rows) -------
// 8 waves/block, one row per wave; lanes 0..47 own 16 consecutive elems.
__global__ __launch_bounds__(512) void conv_i8_kernel(
    const float* __restrict__ src, signed char* __restrict__ dst,
    float* __restrict__ scales)
{
  int w = threadIdx.x >> 6, lane = threadIdx.x & 63;
  int row = blockIdx.x*8 + w;
  const float* r = src + (size_t)row*DIM;
  float x[16]; float mx = 0.f;
  if (lane < 48){
    #pragma unroll
    for (int j = 0; j < 4; ++j){
      float4 v = *(const float4*)(r + lane*16 + j*4);
      x[j*4+0] = v.x; x[j*4+1] = v.y; x[j*4+2] = v.z; x[j*4+3] = v.w;
      mx = fmaxf(mx, fmaxf(fmaxf(fabsf(v.x), fabsf(v.y)), fmaxf(fabsf(v.z), fabsf(v.w))));
    }
  }
  for (int off = 32; off > 0; off >>= 1) mx = fmaxf(mx, __shfl_xor(mx, off, 64));
  if (lane == 0) scales[row] = mx / 127.0f;
  float inv = (mx > 0.f) ? 127.0f / mx : 0.f;
  if (lane < 48){
    int ks = lane >> 2, c = lane & 3;
    uint4 u = packq16(x, inv);
    *(uint4*)(dst + (size_t)row*DIM + ks*64 + ((c ^ (row & 3))*16)) = u;
  }
}

// ---- initial slabs: bf16 [12][2048][128B] + i8 [12][2048][64B] + scales ----
__global__ __launch_bounds__(256) void slab_init(
    const float* __restrict__ pc, unsigned short* __restrict__ slab,
    signed char* __restrict__ sli8, float* __restrict__ spb)
{
  __shared__ __align__(16) float gl[DIM];
  __shared__ float wv[4]; __shared__ float bc;
  int p = blockIdx.x, t = threadIdx.x;
  float a0 = pc[(size_t)p*DIM + t], a1 = pc[(size_t)p*DIM + t + 256],
        a2 = pc[(size_t)p*DIM + t + 512];
  gl[t] = a0; gl[t + 256] = a1; gl[t + 512] = a2;
  float am = fmaxf(fabsf(a0), fmaxf(fabsf(a1), fabsf(a2)));
  for (int off = 32; off > 0; off >>= 1) am = fmaxf(am, __shfl_down(am, off, 64));
  if ((t & 63) == 0) wv[t >> 6] = am;
  __syncthreads();
  if (t == 0) bc = fmaxf(fmaxf(wv[0], wv[1]), fmaxf(wv[2], wv[3]));
  __syncthreads();
  float mx = bc;
  float inv8 = (mx > 0.f) ? 127.0f / mx : 0.f;
  if (t < 96){
    int ks2 = t >> 3, c8 = t & 7;
    const float* sblk = &gl[ks2*64 + c8*8];
    uint4 u = pack8(*(const float4*)sblk, *(const float4*)(sblk + 4));
    *(uint4*)((char*)slab + (((size_t)ks2*NPATCH + p)*128) + ((size_t)(c8 ^ (p & 7))*16)) = u;
  }
  if (t < 48){
    int ks2 = t >> 2, c = t & 3;
    uint4 u = packq16(&gl[t*16], inv8);
    *(uint4*)(sli8 + ((size_t)ks2*NPATCH + p)*64 + ((c ^ (p & 3))*16)) = u;
  }
  if (t == 0) spb[p] = mx / 127.0f;
}

// ---------------- i8 MFMA GEMM (modes 0,1; single-buffer, NT tiles) ----------------
// MODE 0: rows rowbase.., filter >= th, append idx+score
// MODE 1: rows 0..4095, write sims_sample[patch][node]
template<int MODE, int NT>
__global__ __launch_bounds__(256, 3) void gemm8_kernel(
    const signed char* __restrict__ Ai8, const float* __restrict__ sA, int rowbase,
    const signed char* __restrict__ Bslab, const float* __restrict__ sB,
    const float* __restrict__ thresholds,
    int* __restrict__ counters,
    int* __restrict__ cand_idx,
    float* __restrict__ cand_score,
    float* __restrict__ sims_sample,
    const int* __restrict__ active)
{
  if (*active == 0) return;
  __shared__ __align__(16) signed char Al[128*64];
  __shared__ __align__(16) signed char Bl[128*64];
  int b = blockIdx.x, nwg = gridDim.x;
  int wg = (b & 7)*(nwg >> 3) + (b >> 3);   // XCD-chunked swizzle (nwg%8==0)
  int mt0 = (wg >> 4) * NT, pt = wg & 15;
  int t = threadIdx.x, w = t >> 6, lane = t & 63, l15 = lane & 15, l4 = lane >> 4;
  int wr = w >> 1, wc = w & 1;
  int pbase = pt*128;

  float thv[4], sbv[4];
  #pragma unroll
  for (int g = 0; g < 4; ++g){
    int patch = pbase + wc*64 + g*16 + l15;
    if (MODE == 0) thv[g] = thresholds[patch];
    sbv[g] = sB[patch];
  }

  i32x4 acc[4][4];
  #pragma unroll
  for (int x = 0; x < 4; ++x)
    #pragma unroll
    for (int y = 0; y < 4; ++y) acc[x][y] = (i32x4){0, 0, 0, 0};

  const int NSTEP = NT * 12;
  for (int s = 0; s < NSTEP; ++s){
    int tile = s / 12, ks = s % 12;
    if (s) __syncthreads();
    size_t arow0 = (size_t)rowbase + ((size_t)(mt0 + tile))*128;
    // stage: 512 granules x 16B each matrix; wave-uniform LDS base + lane*16
    #pragma unroll
    for (int i = 0; i < 2; ++i){
      int g = w*64 + i*256 + lane;
      const void* ga = Ai8 + (arow0 + (g >> 2))*(size_t)DIM + ks*64 + (g & 3)*16;
      gload16(ga, (char*)Al + (w*64 + i*256)*16);
      const void* gb = Bslab + ((size_t)ks*NPATCH + pbase)*64 + (size_t)g*16;
      gload16(gb, (char*)Bl + (w*64 + i*256)*16);
    }
    __syncthreads();

    i32x4 af[4], bfr[4];
    #pragma unroll
    for (int ng = 0; ng < 4; ++ng){
      int row = wr*64 + ng*16 + l15;
      af[ng] = *(const i32x4*)(Al + row*64 + ((l4 ^ (row & 3))*16));
    }
    #pragma unroll
    for (int g = 0; g < 4; ++g){
      int row = wc*64 + g*16 + l15;
      bfr[g] = *(const i32x4*)(Bl + row*64 + ((l4 ^ (row & 3))*16));
    }
    #pragma unroll
    for (int ng = 0; ng < 4; ++ng)
      #pragma unroll
      for (int g = 0; g < 4; ++g)
        acc[ng][g] = __builtin_amdgcn_mfma_i32_16x16x64_i8(af[ng], bfr[g], acc[ng][g], 0, 0, 0);

    if (ks == 11){
      int nodebase = rowbase + (mt0 + tile)*128 + wr*64;
      if (MODE == 0){
        #pragma unroll
        for (int g = 0; g < 4; ++g){
          int patch = pbase + wc*64 + g*16 + l15;
          float th = thv[g], sb = sbv[g];
          #pragma unroll
          for (int ng = 0; ng < 4; ++ng){
            f32x4 sa = *(const f32x4*)(sA + nodebase + ng*16 + l4*4);
            #pragma unroll
            for (int i = 0; i < 4; ++i){
              float v = (float)acc[ng][g][i] * sa[i] * sb;
              if (v >= th){
                int node = nodebase + ng*16 + l4*4 + i;
                int pos = atomicAdd(&counters[patch], 1);
                if (pos < CAP){
                  cand_idx[(size_t)patch*CAP + pos]   = node;
                  cand_score[(size_t)patch*CAP + pos] = v;
                }
              }
            }
          }
        }
      } else {
        #pragma unroll
        for (int g = 0; g < 4; ++g){
          int patch = pbase + wc*64 + g*16 + l15;
          float sb = sbv[g];
          #pragma unroll
          for (int ng = 0; ng < 4; ++ng){
            f32x4 sa = *(const f32x4*)(sA + nodebase + ng*16 + l4*4);
            f32x4 v;
            #pragma unroll
            for (int i = 0; i < 4; ++i) v[i] = (float)acc[ng][g][i] * sa[i] * sb;
            int col = nodebase + ng*16 + l4*4;
            *(f32x4*)(sims_sample + (size_t)patch*NSAMP + col) = v;
          }
        }
      }
      if (tile + 1 < NT){
        #pragma unroll
        for (int x = 0; x < 4; ++x)
          #pragma unroll
          for (int y = 0; y < 4; ++y) acc[x][y] = (i32x4){0, 0, 0, 0};
      }
    }
  }
}

// ---------------- bf16 evidence GEMM (anchors, rows>=1000 zero) ----------------
__global__ __launch_bounds__(256, 3) void gemm_ev_kernel(
    const unsigned short* __restrict__ Abf,
    const unsigned short* __restrict__ Bslab,
    unsigned* __restrict__ ev_key,
    const int* __restrict__ active)
{
  if (*active == 0) return;
  __shared__ __align__(16) unsigned short Al[128*64];
  __shared__ __align__(16) unsigned short Bl[128*64];
  int b = blockIdx.x, nwg = gridDim.x;
  int wg = (b & 7)*(nwg >> 3) + (b >> 3);
  int mt = wg >> 4, pt = wg & 15;
  int t = threadIdx.x, w = t >> 6, lane = t & 63, l15 = lane & 15, l4 = lane >> 4;
  int wr = w >> 1, wc = w & 1;
  int pbase = pt*128;
  int srow = w*8 + (lane >> 3);
  int scol = (lane & 7)*16;
  const char* Ab = (const char*)Abf;
  const char* Bb = (const char*)Bslab;

  f32x4 acc[4][4];
  #pragma unroll
  for (int x = 0; x < 4; ++x)
    #pragma unroll
    for (int y = 0; y < 4; ++y) acc[x][y] = (f32x4){0.f, 0.f, 0.f, 0.f};

  for (int s = 0; s < 12; ++s){
    if (s) __syncthreads();
    size_t arow0 = (size_t)mt*128;
    #pragma unroll
    for (int i = 0; i < 4; ++i){
      const void* ga = Ab + ((arow0 + srow + i*32)*(size_t)(DIM*2)) + s*128 + scol;
      gload16(ga, (char*)Al + i*4096 + w*1024);
      const void* gb = Bb + (((size_t)s*NPATCH + pbase)*128) + i*4096 + w*1024 + lane*16;
      gload16(gb, (char*)Bl + i*4096 + w*1024);
    }
    __syncthreads();
    short8 af[2][4], bf_[2][4];
    #pragma unroll
    for (int kk = 0; kk < 2; ++kk){
      #pragma unroll
      for (int ng = 0; ng < 4; ++ng){
        int row = wr*64 + ng*16 + l15;
        int slot = (kk*4 + l4) ^ (row & 7);
        af[kk][ng] = *(const short8*)((const char*)Al + row*128 + slot*16);
      }
      #pragma unroll
      for (int g = 0; g < 4; ++g){
        int row = wc*64 + g*16 + l15;
        int slot = (kk*4 + l4) ^ (row & 7);
        bf_[kk][g] = *(const short8*)((const char*)Bl + row*128 + slot*16);
      }
    }
    #pragma unroll
    for (int kk = 0; kk < 2; ++kk)
      #pragma unroll
      for (int ng = 0; ng < 4; ++ng)
        #pragma unroll
        for (int g = 0; g < 4; ++g)
          acc[ng][g] = __builtin_amdgcn_mfma_f32_16x16x32_bf16(af[kk][ng], bf_[kk][g], acc[ng][g], 0, 0, 0);
  }

  #pragma unroll
  for (int g = 0; g < 4; ++g){
    int patch = pbase + wc*64 + g*16 + l15;
    float m = -3e38f; bool any = false;
    #pragma unroll
    for (int ng = 0; ng < 4; ++ng){
      #pragma unroll
      for (int i = 0; i < 4; ++i){
        int a = mt*128 + wr*64 + ng*16 + l4*4 + i;
        if (a < NCLS){ m = fmaxf(m, acc[ng][g][i]); any = true; }
      }
    }
    if (any) atomicMax(&ev_key[patch], encf(m));
  }
}

// -- threshold = 16th max of sampled sims (radix select); append all >= th --
__global__ __launch_bounds__(256) void thresh_kernel(
    const float* __restrict__ sims, float* __restrict__ thresholds,
    int* __restrict__ counters, int* __restrict__ cand_idx,
    float* __restrict__ cand_score, unsigned* __restrict__ ev_key,
    const int* __restrict__ active)
{
  if (*active == 0) return;
  __shared__ unsigned keys[NSAMP];
  __shared__ unsigned hist[258];
  __shared__ int lcnt;
  int p = blockIdx.x, t = threadIdx.x;
  const float4* src = (const float4*)(sims + (size_t)p*NSAMP);
  for (int i = t; i < NSAMP/4; i += 256){
    float4 v = src[i];
    keys[i*4+0] = encf(v.x); keys[i*4+1] = encf(v.y);
    keys[i*4+2] = encf(v.z); keys[i*4+3] = encf(v.w);
  }
  unsigned kth = select_kth(keys, NSAMP, 16, hist, t);
  if (t == 0){ thresholds[p] = decf(kth); ev_key[p] = 0u; lcnt = 0; }
  __syncthreads();
  for (int i = t; i < NSAMP; i += 256){
    unsigned key = keys[i];
    if (key >= kth){
      int pos = atomicAdd(&lcnt, 1);
      if (pos < CAP){
        cand_idx[(size_t)p*CAP + pos]   = i;
        cand_score[(size_t)p*CAP + pos] = decf(key);
      }
    }
  }
  __syncthreads();
  if (t == 0) counters[p] = lcnt < CAP ? lcnt : CAP;
}

// -- radix preselect (top-64 incl. ties) -> exact f32 rescore -> radix exact
//    top-50 (node-id tie-break) -> softmax message + slab updates --
__global__ __launch_bounds__(256) void msg_kernel(
    const int* __restrict__ counters, const int* __restrict__ cand_idx,
    const float* __restrict__ cand_score, const float* __restrict__ memf,
    float* __restrict__ pc, unsigned short* __restrict__ slab,
    signed char* __restrict__ sli8, float* __restrict__ spb,
    const int* __restrict__ active)
{
  if (*active == 0) return;
  __shared__ unsigned sk[CAP]; __shared__ int si[CAP];
  __shared__ __align__(16) float gl[DIM];
  __shared__ unsigned hist[258];
  __shared__ int pn[PCAP]; __shared__ float pv[PCAP];
  __shared__ float selv[64]; __shared__ int seli[64]; __shared__ float attn[64];
  __shared__ float wv[4]; __shared__ float bc;
  __shared__ int cnt2;
  int p = blockIdx.x, t = threadIdx.x;
  int n = counters[p]; if (n > CAP) n = CAP;
  #pragma unroll
  for (int j = 0; j < 3; ++j) gl[t + j*256] = pc[(size_t)p*DIM + t + j*256];
  for (int i = t; i < CAP; i += 256){
    sk[i] = (i < n) ? encf(cand_score[(size_t)p*CAP + i]) : 0u;
    si[i] = (i < n) ? cand_idx[(size_t)p*CAP + i] : 0;
  }
  unsigned kth64 = 1u;
  if (n > PRESEL) kth64 = select_kth(sk, n, PRESEL, hist, t);
  else            __syncthreads();
  if (t == 0) cnt2 = 0;
  __syncthreads();
  for (int i = t; i < n; i += 256){
    if (sk[i] >= kth64){
      int pos = atomicAdd(&cnt2, 1);
      if (pos < PCAP) pn[pos] = si[i];
    }
  }
  __syncthreads();
  int m = cnt2 < PCAP ? cnt2 : PCAP;
  // exact f32 rescore
  int w = t >> 6, lane = t & 63;
  for (int i = w; i < m; i += 4){
    const float* row = memf + (size_t)pn[i]*DIM;
    float s = 0.f;
    #pragma unroll
    for (int j = 0; j < 12; ++j){
      int d = lane + j*64;
      s += row[d] * gl[d];
    }
    for (int off = 32; off > 0; off >>= 1) s += __shfl_down(s, off, 64);
    if (lane == 0) pv[i] = s;
  }
  __syncthreads();
  int K = m < 50 ? m : 50;
  if (t < m) sk[t] = encf(pv[t]);
  unsigned kth50 = 1u;
  if (m > K) kth50 = select_kth(sk, m, K, hist, t);
  else       __syncthreads();
  if (t == 0) cnt2 = 0;
  __syncthreads();
  if (t < m && sk[t] > kth50){
    int pos = atomicAdd(&cnt2, 1);
    seli[pos] = pn[t]; selv[pos] = pv[t];
    sk[t] = 0u;
  }
  __syncthreads();
  if (t == 0){                             // boundary ties: smallest node id first
    int c = cnt2;
    for (int j = c; j < K; ++j){
      int best = -1, bestnode = 0x7FFFFFFF;
      for (int i = 0; i < m; ++i)
        if (sk[i] == kth50 && pn[i] < bestnode){ best = i; bestnode = pn[i]; }
      if (best < 0) break;
      seli[j] = pn[best]; selv[j] = pv[best]; sk[best] = 0u;
    }
  }
  __syncthreads();
  float v = (t < K) ? selv[t] : -3e38f;
  for (int off = 32; off > 0; off >>= 1) v = fmaxf(v, __shfl_down(v, off, 64));
  if ((t & 63) == 0) wv[t >> 6] = v;
  __syncthreads();
  if (t == 0) bc = fmaxf(fmaxf(wv[0], wv[1]), fmaxf(wv[2], wv[3]));
  __syncthreads();
  float vmax = bc;
  __syncthreads();
  if (t < K) attn[t] = __expf((selv[t] - vmax) * TAUINV);
  __syncthreads();
  if (t == 0){ float s = 0.f; for (int k = 0; k < K; ++k) s += attn[k]; bc = s; }
  __syncthreads();
  float inv = 1.0f / bc;
  int d0 = t, d1 = t + 256, d2 = t + 512;
  float a0 = gl[d0], a1 = gl[d1], a2 = gl[d2];
  for (int k = 0; k < K; ++k){
    float a = attn[k] * inv;
    const float* row = memf + (size_t)seli[k]*DIM;
    a0 += a * row[d0]; a1 += a * row[d1]; a2 += a * row[d2];
  }
  float ss = a0*a0 + a1*a1 + a2*a2;
  for (int off = 32; off > 0; off >>= 1) ss += __shfl_down(ss, off, 64);
  if ((t & 63) == 0) wv[t >> 6] = ss;
  __syncthreads();
  if (t == 0) bc = wv[0] + wv[1] + wv[2] + wv[3];
  __syncthreads();
  float rn = 1.0f / fmaxf(sqrtf(bc), 1e-12f);
  a0 *= rn; a1 *= rn; a2 *= rn;
  float* orow = pc + (size_t)p*DIM;
  orow[d0] = a0; orow[d1] = a1; orow[d2] = a2;
  float am = fmaxf(fabsf(a0), fmaxf(fabsf(a1), fabsf(a2)));
  for (int off = 32; off > 0; off >>= 1) am = fmaxf(am, __shfl_down(am, off, 64));
  __syncthreads();
  gl[d0] = a0; gl[d1] = a1; gl[d2] = a2;
  if ((t & 63) == 0) wv[t >> 6] = am;
  __syncthreads();
  if (t == 0) bc = fmaxf(fmaxf(wv[0], wv[1]), fmaxf(wv[2], wv[3]));
  __syncthreads();
  float mx = bc;
  float inv8 = (mx > 0.f) ? 127.0f / mx : 0.f;
  if (t < 96){
    int ks2 = t >> 3, c8 = t & 7;
    const float* sblk = &gl[ks2*64 + c8*8];
    uint4 u = pack8(*(const float4*)sblk, *(const float4*)(sblk + 4));
    *(uint4*)((char*)slab + (((size_t)ks2*NPATCH + p)*128) + ((size_t)(c8 ^ (p & 7))*16)) = u;
  }
  if (t < 48){
    int ks2 = t >> 2, c = t & 3;
    uint4 u = packq16(&gl[t*16], inv8);
    *(uint4*)(sli8 + ((size_t)ks2*NPATCH + p)*64 + ((c ^ (p & 3))*16)) = u;
  }
  if (t == 0) spb[p] = mx / 127.0f;
}

// ---------------- evidence softmax stats + weighted pooling partials ----------------
__global__ __launch_bounds__(256) void pl2_kernel(
    const unsigned* __restrict__ ev_key, const float* __restrict__ pc,
    float* __restrict__ g_part, const int* __restrict__ active)
{
  if (*active == 0) return;
  __shared__ float wv[4]; __shared__ float bc;
  int t = threadIdx.x;
  float m = -3e38f;
  for (int i = t; i < NPATCH; i += 256) m = fmaxf(m, decf(ev_key[i]));
  for (int off = 32; off > 0; off >>= 1) m = fmaxf(m, __shfl_down(m, off, 64));
  if ((t & 63) == 0) wv[t >> 6] = m;
  __syncthreads();
  if (t == 0) bc = fmaxf(fmaxf(wv[0], wv[1]), fmaxf(wv[2], wv[3]));
  __syncthreads();
  float M = bc;
  __syncthreads();
  float s = 0.f;
  for (int i = t; i < NPATCH; i += 256) s += __expf((decf(ev_key[i]) - M) * TAUINV);
  for (int off = 32; off > 0; off >>= 1) s += __shfl_down(s, off, 64);
  if ((t & 63) == 0) wv[t >> 6] = s;
  __syncthreads();
  if (t == 0) bc = wv[0] + wv[1] + wv[2] + wv[3];
  __syncthreads();
  float invS = 1.0f / bc;
  int pbase = blockIdx.x * 64;
  float a0 = 0.f, a1 = 0.f, a2 = 0.f;
  for (int i = 0; i < 64; ++i){
    int p = pbase + i;
    float wgt = __expf((decf(ev_key[p]) - M) * TAUINV) * invS;
    const float* row = pc + (size_t)p*DIM;
    a0 += wgt * row[t]; a1 += wgt * row[t + 256]; a2 += wgt * row[t + 512];
  }
  g_part[blockIdx.x*DIM + t]       = a0;
  g_part[blockIdx.x*DIM + t + 256] = a1;
  g_part[blockIdx.x*DIM + t + 512] = a2;
}

// ------- logits + entropy + commit (INIT: g=tg; else reduce g_part + norm) -------
template<bool INIT>
__global__ __launch_bounds__(256) void cm_kernel(
    const float* __restrict__ gsrc, const float* __restrict__ protos,
    float* __restrict__ logits_cur, int* __restrict__ step, int* __restrict__ active)
{
  if (!INIT && *active == 0) return;
  __shared__ __align__(16) float gl[DIM];
  __shared__ float lg[NCLS];
  __shared__ float wv[4]; __shared__ float bc;
  int t = threadIdx.x;
  if (INIT){
    #pragma unroll
    for (int j = 0; j < 3; ++j) gl[t + j*256] = gsrc[t + j*256];
  } else {
    float gv[3]; float ss = 0.f;
    #pragma unroll
    for (int j = 0; j < 3; ++j){
      int d = t + j*256;
      float s = 0.f;
      for (int b2 = 0; b2 < 32; ++b2) s += gsrc[b2*DIM + d];
      gv[j] = s; ss += s*s;
    }
    for (int off = 32; off > 0; off >>= 1) ss += __shfl_down(ss, off, 64);
    if ((t & 63) == 0) wv[t >> 6] = ss;
    __syncthreads();
    if (t == 0) bc = wv[0] + wv[1] + wv[2] + wv[3];
    __syncthreads();
    float rn = 1.0f / fmaxf(sqrtf(bc), 1e-12f);
    #pragma unroll
    for (int j = 0; j < 3; ++j) gl[t + j*256] = gv[j] * rn;
  }
  __syncthreads();
  for (int c = t; c < NCLS; c += 256){
    const float4* pr = (const float4*)(protos + (size_t)c*DIM);
    float s = 0.f;
    #pragma unroll 4
    for (int d4 = 0; d4 < DIM/4; ++d4){
      float4 pv = pr[d4];
      float4 gv = *(const float4*)&gl[d4*4];
      s += gv.x*pv.x + gv.y*pv.y + gv.z*pv.z + gv.w*pv.w;
    }
    float L = 100.0f * s;
    lg[c] = L; logits_cur[c] = L;
  }
  __syncthreads();
  float m = -3e38f;
  for (int c = t; c < NCLS; c += 256) m = fmaxf(m, lg[c]);
  for (int off = 32; off > 0; off >>= 1) m = fmaxf(m, __shfl_down(m, off, 64));
  if ((t & 63) == 0) wv[t >> 6] = m;
  __syncthreads();
  if (t == 0) bc = fmaxf(fmaxf(wv[0], wv[1]), fmaxf(wv[2], wv[3]));
  __syncthreads();
  float M = bc;
  __syncthreads();
  float s = 0.f;
  for (int c = t; c < NCLS; c += 256) s += __expf(lg[c] - M);
  for (int off = 32; off > 0; off >>= 1) s += __shfl_down(s, off, 64);
  if ((t & 63) == 0) wv[t >> 6] = s;
  __syncthreads();
  if (t == 0) bc = wv[0] + wv[1] + wv[2] + wv[3];
  __syncthreads();
  float S = bc;
  __syncthreads();
  float hp = 0.f;
  for (int c = t; c < NCLS; c += 256){
    float pcl = __expf(lg[c] - M) / S;
    hp += pcl * __logf(pcl + 1e-10f);
  }
  for (int off = 32; off > 0; off >>= 1) hp += __shfl_down(hp, off, 64);
  if ((t & 63) == 0) wv[t >> 6] = hp;
  __syncthreads();
  if (t == 0){
    float H = -(wv[0] + wv[1] + wv[2] + wv[3]);
    if (INIT){ *step = 0; *active = (H > 0.8f) ? 1 : 0; }
    else     { *step = *step + 1; *active = (H > 0.8f) ? 1 : 0; }
  }
}

// ---------------- publish ----------------
__global__ void pub_kernel(const float* __restrict__ logits_cur, const int* __restrict__ step,
                           float* __restrict__ out)
{
  int i = blockIdx.x*256 + threadIdx.x;
  if (i < NCLS) out[i] = logits_cur[i];
  else if (i == NCLS) out[i] = (float)(*step);
}

extern "C" void kernel_launch(void* const* d_in, const int* in_sizes, int n_in,
                              void* d_out, int out_size, void* d_ws, size_t ws_size,
                              hipStream_t stream)
{
  (void)in_sizes; (void)n_in; (void)out_size; (void)ws_size;
  const float* tg  = (const float*)d_in[0];   // [1,768]
  const float* tp  = (const float*)d_in[1];   // [2048,768]
  const float* mem = (const float*)d_in[2];   // [65536,768]
  const float* anc = (const float*)d_in[3];   // [1000,768]
  const float* cs  = (const float*)d_in[4];   // [1000,768]
  const float* cc  = (const float*)d_in[5];   // [1000]

  char* ws = (char*)d_ws;
  auto al = [](size_t x){ return (x + 255) & ~(size_t)255; };
  size_t OFF_PC   = 0;
  size_t OFF_PROT = al(OFF_PC   + (size_t)NPATCH*DIM*4);
  size_t OFF_ABF  = al(OFF_PROT + (size_t)NCLS*DIM*4);
  size_t OFF_MI8  = al(OFF_ABF  + (size_t)1024*DIM*2);
  size_t OFF_SA   = al(OFF_MI8  + (size_t)NMEM*DIM);
  size_t OFF_SLAB = al(OFF_SA   + (size_t)NMEM*4);
  size_t OFF_SLI8 = al(OFF_SLAB + (size_t)NPATCH*DIM*2);
  size_t OFF_SPB  = al(OFF_SLI8 + (size_t)NPATCH*DIM);
  size_t OFF_SS   = al(OFF_SPB  + (size_t)NPATCH*4);
  size_t OFF_THR  = al(OFF_SS   + (size_t)NPATCH*NSAMP*4);
  size_t OFF_CNT  = al(OFF_THR  + (size_t)NPATCH*4);
  size_t OFF_CI   = al(OFF_CNT  + (size_t)NPATCH*4);
  size_t OFF_CSC  = al(OFF_CI   + (size_t)NPATCH*CAP*4);
  size_t OFF_EV   = al(OFF_CSC  + (size_t)NPATCH*CAP*4);
  size_t OFF_GP   = al(OFF_EV   + (size_t)NPATCH*4);
  size_t OFF_LC   = al(OFF_GP   + (size_t)32*DIM*4);
  size_t OFF_STEP = al(OFF_LC   + (size_t)NCLS*4);

  float*          pc      = (float*)(ws + OFF_PC);
  float*          protos  = (float*)(ws + OFF_PROT);
  unsigned short* abf     = (unsigned short*)(ws + OFF_ABF);
  signed char*    mi8     = (signed char*)(ws + OFF_MI8);
  float*          sa      = (float*)(ws + OFF_SA);
  unsigned short* slab    = (unsigned short*)(ws + OFF_SLAB);
  signed char*    sli8    = (signed char*)(ws + OFF_SLI8);
  float*          spb     = (float*)(ws + OFF_SPB);
  float*          simss   = (float*)(ws + OFF_SS);
  float*          thr     = (float*)(ws + OFF_THR);
  int*            cnt     = (int*)(ws + OFF_CNT);
  int*            ci      = (int*)(ws + OFF_CI);
  float*          csc     = (float*)(ws + OFF_CSC);
  unsigned*       evk     = (unsigned*)(ws + OFF_EV);
  float*          gp      = (float*)(ws + OFF_GP);
  float*          lc      = (float*)(ws + OFF_LC);
  int*            stepp   = (int*)(ws + OFF_STEP);
  int*            activep = stepp + 1;

  proto_kernel<<<1024, 256, 0, stream>>>(anc, cs, cc, protos, abf);
  prep_patches<<<(NPATCH*DIM/4)/256, 256, 0, stream>>>(tp, pc);
  conv_i8_kernel<<<NMEM/8, 512, 0, stream>>>(mem, mi8, sa);
  cm_kernel<true><<<1, 256, 0, stream>>>(tg, protos, lc, stepp, activep);
  slab_init<<<NPATCH, 256, 0, stream>>>(pc, slab, sli8, spb);

  for (int it = 0; it < 3; ++it){
    gemm8_kernel<1,1><<<(NSAMP/128)*16, 256, 0, stream>>>(
        mi8, sa, 0, sli8, spb, thr, cnt, ci, csc, simss, activep);
    thresh_kernel<<<NPATCH, 256, 0, stream>>>(simss, thr, cnt, ci, csc, evk, activep);
    gemm8_kernel<0,4><<<((NMEM-NSAMP)/512)*16, 256, 0, stream>>>(
        mi8, sa, NSAMP, sli8, spb, thr, cnt, ci, csc, simss, activep);
    msg_kernel<<<NPATCH, 256, 0, stream>>>(cnt, ci, csc, mem, pc, slab, sli8, spb, activep);
    gemm_ev_kernel<<<(1024/128)*16, 256, 0, stream>>>(abf, slab, evk, activep);
    pl2_kernel<<<32, 256, 0, stream>>>(evk, pc, gp, activep);
    cm_kernel<false><<<1, 256, 0, stream>>>(gp, protos, lc, stepp, activep);
  }
  pub_kernel<<<4, 256, 0, stream>>>(lc, stepp, (float*)d_out);
}

// Round 10
// 1738.767 us; speedup vs baseline: 1.4779x; 1.0125x over previous
//
#include <hip/hip_runtime.h>
#include <hip/hip_bf16.h>
#include <stdint.h>

// ContinuousEpisodicVLM: 3-step episodic retrieval loop.
// i8 MFMA candidate generation (2x bf16 rate; per-row scales) + radix-select
// top-64(+ties) preselect + exact f32 rescore + radix exact top-50 + softmax
// message. Evidence GEMM stays bf16 (error-chain isolation).
// i8 LDS swizzle: slot = chunk ^ ((row>>1)&3)  -- row stride is 64B = half a
// bank rotation, so the swizzle key must advance once per TWO rows to cover
// all 8 bank-quad offsets (round-9 lesson: key=row&3 gave 4-way conflicts).

typedef __attribute__((ext_vector_type(8))) short short8;
typedef __attribute__((ext_vector_type(4))) float f32x4;
typedef __attribute__((ext_vector_type(4))) int   i32x4;

#define DIM    768
#define NPATCH 2048
#define NMEM   65536
#define NCLS   1000
#define NSAMP  4096   // sample = first 4096 rows
#define CAP    1024   // candidate buffer per patch
#define PRESEL 64     // preselection rank
#define PCAP   128    // preselection buffer (ties headroom)
#define TAUINV 50.0f  // 1/0.02

__device__ __forceinline__ unsigned short f2bf(float f){
  unsigned b = __float_as_uint(f);
  b += 0x7FFFu + ((b >> 16) & 1u);      // RNE
  return (unsigned short)(b >> 16);
}
__device__ __forceinline__ unsigned encf(float x){
  unsigned b = __float_as_uint(x);
  return (b & 0x80000000u) ? ~b : (b | 0x80000000u);   // order-preserving
}
__device__ __forceinline__ float decf(unsigned k){
  unsigned b = (k & 0x80000000u) ? (k & 0x7FFFFFFFu) : ~k;
  return __uint_as_float(b);
}
__device__ __forceinline__ void gload16(const void* g, void* l){
  __builtin_amdgcn_global_load_lds(
      (const __attribute__((address_space(1))) unsigned int*)g,
      (__attribute__((address_space(3))) unsigned int*)l, 16, 0, 0);
}
__device__ __forceinline__ uint4 pack8(float4 a, float4 b){
  uint4 u;
  u.x = (unsigned)f2bf(a.x) | ((unsigned)f2bf(a.y) << 16);
  u.y = (unsigned)f2bf(a.z) | ((unsigned)f2bf(a.w) << 16);
  u.z = (unsigned)f2bf(b.x) | ((unsigned)f2bf(b.y) << 16);
  u.w = (unsigned)f2bf(b.z) | ((unsigned)f2bf(b.w) << 16);
  return u;
}
__device__ __forceinline__ uint4 packq16(const float* s, float inv){
  unsigned wd[4];
  #pragma unroll
  for (int k = 0; k < 4; ++k){
    unsigned v = 0;
    #pragma unroll
    for (int j = 0; j < 4; ++j){
      int q = __float2int_rn(s[k*4 + j] * inv);
      q = q > 127 ? 127 : (q < -127 ? -127 : q);
      v |= ((unsigned)(q & 255)) << (8*j);
    }
    wd[k] = v;
  }
  return make_uint4(wd[0], wd[1], wd[2], wd[3]);
}

// ---- exact k-th largest of keys[0..n) via 4x8-bit radix histogram ----
__device__ __forceinline__ unsigned select_kth(const unsigned* keys, int n, int k,
                                               unsigned* hist, int t)
{
  __syncthreads();
  if (t == 0){ hist[256] = 0u; hist[257] = (unsigned)k; }
  __syncthreads();
  for (int pass = 0; pass < 4; ++pass){
    int shift = 24 - 8*pass;
    hist[t] = 0u;
    __syncthreads();
    unsigned pref = hist[256];
    for (int i = t; i < n; i += 256){
      unsigned key = keys[i];
      bool ok = (pass == 0) || ((key >> (shift + 8)) == pref);
      if (ok) atomicAdd(&hist[(key >> shift) & 255u], 1u);
    }
    __syncthreads();
    if (t == 0){
      unsigned krem = hist[257];
      unsigned cum = 0u; int b = 255;
      for (; b >= 0; --b){ cum += hist[b]; if (cum >= krem) break; }
      if (b < 0) b = 0;
      unsigned above = cum - hist[b];
      hist[257] = krem - above;
      hist[256] = (pref << 8) | (unsigned)b;
    }
    __syncthreads();
  }
  return hist[256];
}

// ---------------- protos + anchors_bf16 (pre-swizzled, 128B-row XOR) ----------------
__global__ __launch_bounds__(256) void proto_kernel(
    const float* __restrict__ anchors, const float* __restrict__ sums,
    const float* __restrict__ counts, float* __restrict__ protos,
    unsigned short* __restrict__ anchors_bf)
{
  int c = blockIdx.x, t = threadIdx.x;
  if (c >= NCLS){
    for (int j = 0; j < 3; ++j) anchors_bf[(size_t)c*DIM + t + j*256] = 0;
    return;
  }
  __shared__ float wv[4]; __shared__ float bc;
  float cnt = fmaxf(counts[c], 1.0f);
  float v[3];
  #pragma unroll
  for (int j = 0; j < 3; ++j) v[j] = sums[(size_t)c*DIM + t + j*256] / cnt;
  float ss = v[0]*v[0] + v[1]*v[1] + v[2]*v[2];
  for (int off = 32; off > 0; off >>= 1) ss += __shfl_down(ss, off, 64);
  if ((t & 63) == 0) wv[t >> 6] = ss;
  __syncthreads();
  if (t == 0) bc = wv[0] + wv[1] + wv[2] + wv[3];
  __syncthreads();
  float rn = 1.0f / fmaxf(sqrtf(bc), 1e-12f);
  __syncthreads();
  float pr[3];
  #pragma unroll
  for (int j = 0; j < 3; ++j){
    int d = t + j*256;
    float a = anchors[(size_t)c*DIM + d];
    pr[j] = a + v[j] * rn;                         // ALPHA = 1.0
    int dd = (d & ~63) | ((((d >> 3) ^ c) & 7) << 3) | (d & 7);
    anchors_bf[(size_t)c*DIM + dd] = f2bf(a);
  }
  ss = pr[0]*pr[0] + pr[1]*pr[1] + pr[2]*pr[2];
  for (int off = 32; off > 0; off >>= 1) ss += __shfl_down(ss, off, 64);
  if ((t & 63) == 0) wv[t >> 6] = ss;
  __syncthreads();
  if (t == 0) bc = wv[0] + wv[1] + wv[2] + wv[3];
  __syncthreads();
  float rn2 = 1.0f / fmaxf(sqrtf(bc), 1e-12f);
  #pragma unroll
  for (int j = 0; j < 3; ++j) protos[(size_t)c*DIM + t + j*256] = pr[j] * rn2;
}

// ---------------- patches f32 working copy ----------------
__global__ __launch_bounds__(256) void prep_patches(
    const float* __restrict__ tp, float* __restrict__ pc)
{
  size_t i = (size_t)blockIdx.x*256 + threadIdx.x;
  *(float4*)(pc + i*4) = *(const float4*)(tp + i*4);
}

// ------- memory f32 -> per-row-scaled i8 (chunk-swizzled 64B rows) -------
__global__ __launch_bounds__(512) void conv_i8_kernel(
    const float* __restrict__ src, signed char* __restrict__ dst,
    float* __restrict__ scales)
{
  int w = threadIdx.x >> 6, lane = threadIdx.x & 63;
  int row = blockIdx.x*8 + w;
  const float* r = src + (size_t)row*DIM;
  float x[16]; float mx = 0.f;
  if (lane < 48){
    #pragma unroll
    for (int j = 0; j < 4; ++j){
      float4 v = *(const float4*)(r + lane*16 + j*4);
      x[j*4+0] = v.x; x[j*4+1] = v.y; x[j*4+2] = v.z; x[j*4+3] = v.w;
      mx = fmaxf(mx, fmaxf(fmaxf(fabsf(v.x), fabsf(v.y)), fmaxf(fabsf(v.z), fabsf(v.w))));
    }
  }
  for (int off = 32; off > 0; off >>= 1) mx = fmaxf(mx, __shfl_xor(mx, off, 64));
  if (lane == 0) scales[row] = mx / 127.0f;
  float inv = (mx > 0.f) ? 127.0f / mx : 0.f;
  if (lane < 48){
    int ks = lane >> 2, c = lane & 3;
    uint4 u = packq16(x, inv);
    *(uint4*)(dst + (size_t)row*DIM + ks*64 + ((c ^ ((row >> 1) & 3))*16)) = u;
  }
}

// ---- initial slabs: bf16 [12][2048][128B] + i8 [12][2048][64B] + scales ----
__global__ __launch_bounds__(256) void slab_init(
    const float* __restrict__ pc, unsigned short* __restrict__ slab,
    signed char* __restrict__ sli8, float* __restrict__ spb)
{
  __shared__ __align__(16) float gl[DIM];
  __shared__ float wv[4]; __shared__ float bc;
  int p = blockIdx.x, t = threadIdx.x;
  float a0 = pc[(size_t)p*DIM + t], a1 = pc[(size_t)p*DIM + t + 256],
        a2 = pc[(size_t)p*DIM + t + 512];
  gl[t] = a0; gl[t + 256] = a1; gl[t + 512] = a2;
  float am = fmaxf(fabsf(a0), fmaxf(fabsf(a1), fabsf(a2)));
  for (int off = 32; off > 0; off >>= 1) am = fmaxf(am, __shfl_down(am, off, 64));
  if ((t & 63) == 0) wv[t >> 6] = am;
  __syncthreads();
  if (t == 0) bc = fmaxf(fmaxf(wv[0], wv[1]), fmaxf(wv[2], wv[3]));
  __syncthreads();
  float mx = bc;
  float inv8 = (mx > 0.f) ? 127.0f / mx : 0.f;
  if (t < 96){
    int ks2 = t >> 3, c8 = t & 7;
    const float* sblk = &gl[ks2*64 + c8*8];
    uint4 u = pack8(*(const float4*)sblk, *(const float4*)(sblk + 4));
    *(uint4*)((char*)slab + (((size_t)ks2*NPATCH + p)*128) + ((size_t)(c8 ^ (p & 7))*16)) = u;
  }
  if (t < 48){
    int ks2 = t >> 2, c = t & 3;
    uint4 u = packq16(&gl[t*16], inv8);
    *(uint4*)(sli8 + ((size_t)ks2*NPATCH + p)*64 + ((c ^ ((p >> 1) & 3))*16)) = u;
  }
  if (t == 0) spb[p] = mx / 127.0f;
}

// ---------------- i8 MFMA GEMM (modes 0,1; single-buffer, NT tiles) ----------------
template<int MODE, int NT>
__global__ __launch_bounds__(256, 3) void gemm8_kernel(
    const signed char* __restrict__ Ai8, const float* __restrict__ sA, int rowbase,
    const signed char* __restrict__ Bslab, const float* __restrict__ sB,
    const float* __restrict__ thresholds,
    int* __restrict__ counters,
    int* __restrict__ cand_idx,
    float* __restrict__ cand_score,
    float* __restrict__ sims_sample,
    const int* __restrict__ active)
{
  if (*active == 0) return;
  __shared__ __align__(16) signed char Al[128*64];
  __shared__ __align__(16) signed char Bl[128*64];
  int b = blockIdx.x, nwg = gridDim.x;
  int wg = (b & 7)*(nwg >> 3) + (b >> 3);   // XCD-chunked swizzle (nwg%8==0)
  int mt0 = (wg >> 4) * NT, pt = wg & 15;
  int t = threadIdx.x, w = t >> 6, lane = t & 63, l15 = lane & 15, l4 = lane >> 4;
  int wr = w >> 1, wc = w & 1;
  int pbase = pt*128;

  float thv[4], sbv[4];
  #pragma unroll
  for (int g = 0; g < 4; ++g){
    int patch = pbase + wc*64 + g*16 + l15;
    if (MODE == 0) thv[g] = thresholds[patch];
    sbv[g] = sB[patch];
  }

  i32x4 acc[4][4];
  #pragma unroll
  for (int x = 0; x < 4; ++x)
    #pragma unroll
    for (int y = 0; y < 4; ++y) acc[x][y] = (i32x4){0, 0, 0, 0};

  const int NSTEP = NT * 12;
  for (int s = 0; s < NSTEP; ++s){
    int tile = s / 12, ks = s % 12;
    if (s) __syncthreads();
    size_t arow0 = (size_t)rowbase + ((size_t)(mt0 + tile))*128;
    #pragma unroll
    for (int i = 0; i < 2; ++i){
      int g = w*64 + i*256 + lane;
      const void* ga = Ai8 + (arow0 + (g >> 2))*(size_t)DIM + ks*64 + (g & 3)*16;
      gload16(ga, (char*)Al + (w*64 + i*256)*16);
      const void* gb = Bslab + ((size_t)ks*NPATCH + pbase)*64 + (size_t)g*16;
      gload16(gb, (char*)Bl + (w*64 + i*256)*16);
    }
    __syncthreads();

    i32x4 af[4], bfr[4];
    #pragma unroll
    for (int ng = 0; ng < 4; ++ng){
      int row = wr*64 + ng*16 + l15;
      af[ng] = *(const i32x4*)(Al + row*64 + ((l4 ^ ((row >> 1) & 3))*16));
    }
    #pragma unroll
    for (int g = 0; g < 4; ++g){
      int row = wc*64 + g*16 + l15;
      bfr[g] = *(const i32x4*)(Bl + row*64 + ((l4 ^ ((row >> 1) & 3))*16));
    }
    #pragma unroll
    for (int ng = 0; ng < 4; ++ng)
      #pragma unroll
      for (int g = 0; g < 4; ++g)
        acc[ng][g] = __builtin_amdgcn_mfma_i32_16x16x64_i8(af[ng], bfr[g], acc[ng][g], 0, 0, 0);

    if (ks == 11){
      int nodebase = rowbase + (mt0 + tile)*128 + wr*64;
      if (MODE == 0){
        #pragma unroll
        for (int g = 0; g < 4; ++g){
          int patch = pbase + wc*64 + g*16 + l15;
          float th = thv[g], sb = sbv[g];
          #pragma unroll
          for (int ng = 0; ng < 4; ++ng){
            f32x4 sa = *(const f32x4*)(sA + nodebase + ng*16 + l4*4);
            #pragma unroll
            for (int i = 0; i < 4; ++i){
              float v = (float)acc[ng][g][i] * sa[i] * sb;
              if (v >= th){
                int node = nodebase + ng*16 + l4*4 + i;
                int pos = atomicAdd(&counters[patch], 1);
                if (pos < CAP){
                  cand_idx[(size_t)patch*CAP + pos]   = node;
                  cand_score[(size_t)patch*CAP + pos] = v;
                }
              }
            }
          }
        }
      } else {
        #pragma unroll
        for (int g = 0; g < 4; ++g){
          int patch = pbase + wc*64 + g*16 + l15;
          float sb = sbv[g];
          #pragma unroll
          for (int ng = 0; ng < 4; ++ng){
            f32x4 sa = *(const f32x4*)(sA + nodebase + ng*16 + l4*4);
            f32x4 v;
            #pragma unroll
            for (int i = 0; i < 4; ++i) v[i] = (float)acc[ng][g][i] * sa[i] * sb;
            int col = nodebase + ng*16 + l4*4;
            *(f32x4*)(sims_sample + (size_t)patch*NSAMP + col) = v;
          }
        }
      }
      if (tile + 1 < NT){
        #pragma unroll
        for (int x = 0; x < 4; ++x)
          #pragma unroll
          for (int y = 0; y < 4; ++y) acc[x][y] = (i32x4){0, 0, 0, 0};
      }
    }
  }
}

// ---------------- bf16 evidence GEMM (anchors, rows>=1000 zero) ----------------
__global__ __launch_bounds__(256, 3) void gemm_ev_kernel(
    const unsigned short* __restrict__ Abf,
    const unsigned short* __restrict__ Bslab,
    unsigned* __restrict__ ev_key,
    const int* __restrict__ active)
{
  if (*active == 0) return;
  __shared__ __align__(16) unsigned short Al[128*64];
  __shared__ __align__(16) unsigned short Bl[128*64];
  int b = blockIdx.x, nwg = gridDim.x;
  int wg = (b & 7)*(nwg >> 3) + (b >> 3);
  int mt = wg >> 4, pt = wg & 15;
  int t = threadIdx.x, w = t >> 6, lane = t & 63, l15 = lane & 15, l4 = lane >> 4;
  int wr = w >> 1, wc = w & 1;
  int pbase = pt*128;
  int srow = w*8 + (lane >> 3);
  int scol = (lane & 7)*16;
  const char* Ab = (const char*)Abf;
  const char* Bb = (const char*)Bslab;

  f32x4 acc[4][4];
  #pragma unroll
  for (int x = 0; x < 4; ++x)
    #pragma unroll
    for (int y = 0; y < 4; ++y) acc[x][y] = (f32x4){0.f, 0.f, 0.f, 0.f};

  for (int s = 0; s < 12; ++s){
    if (s) __syncthreads();
    size_t arow0 = (size_t)mt*128;
    #pragma unroll
    for (int i = 0; i < 4; ++i){
      const void* ga = Ab + ((arow0 + srow + i*32)*(size_t)(DIM*2)) + s*128 + scol;
      gload16(ga, (char*)Al + i*4096 + w*1024);
      const void* gb = Bb + (((size_t)s*NPATCH + pbase)*128) + i*4096 + w*1024 + lane*16;
      gload16(gb, (char*)Bl + i*4096 + w*1024);
    }
    __syncthreads();
    short8 af[2][4], bf_[2][4];
    #pragma unroll
    for (int kk = 0; kk < 2; ++kk){
      #pragma unroll
      for (int ng = 0; ng < 4; ++ng){
        int row = wr*64 + ng*16 + l15;
        int slot = (kk*4 + l4) ^ (row & 7);
        af[kk][ng] = *(const short8*)((const char*)Al + row*128 + slot*16);
      }
      #pragma unroll
      for (int g = 0; g < 4; ++g){
        int row = wc*64 + g*16 + l15;
        int slot = (kk*4 + l4) ^ (row & 7);
        bf_[kk][g] = *(const short8*)((const char*)Bl + row*128 + slot*16);
      }
    }
    #pragma unroll
    for (int kk = 0; kk < 2; ++kk)
      #pragma unroll
      for (int ng = 0; ng < 4; ++ng)
        #pragma unroll
        for (int g = 0; g < 4; ++g)
          acc[ng][g] = __builtin_amdgcn_mfma_f32_16x16x32_bf16(af[kk][ng], bf_[kk][g], acc[ng][g], 0, 0, 0);
  }

  #pragma unroll
  for (int g = 0; g < 4; ++g){
    int patch = pbase + wc*64 + g*16 + l15;
    float m = -3e38f; bool any = false;
    #pragma unroll
    for (int ng = 0; ng < 4; ++ng){
      #pragma unroll
      for (int i = 0; i < 4; ++i){
        int a = mt*128 + wr*64 + ng*16 + l4*4 + i;
        if (a < NCLS){ m = fmaxf(m, acc[ng][g][i]); any = true; }
      }
    }
    if (any) atomicMax(&ev_key[patch], encf(m));
  }
}

// -- threshold = 16th max of sampled sims (radix select); append all >= th --
__global__ __launch_bounds__(256) void thresh_kernel(
    const float* __restrict__ sims, float* __restrict__ thresholds,
    int* __restrict__ counters, int* __restrict__ cand_idx,
    float* __restrict__ cand_score, unsigned* __restrict__ ev_key,
    const int* __restrict__ active)
{
  if (*active == 0) return;
  __shared__ unsigned keys[NSAMP];
  __shared__ unsigned hist[258];
  __shared__ int lcnt;
  int p = blockIdx.x, t = threadIdx.x;
  const float4* src = (const float4*)(sims + (size_t)p*NSAMP);
  for (int i = t; i < NSAMP/4; i += 256){
    float4 v = src[i];
    keys[i*4+0] = encf(v.x); keys[i*4+1] = encf(v.y);
    keys[i*4+2] = encf(v.z); keys[i*4+3] = encf(v.w);
  }
  unsigned kth = select_kth(keys, NSAMP, 16, hist, t);
  if (t == 0){ thresholds[p] = decf(kth); ev_key[p] = 0u; lcnt = 0; }
  __syncthreads();
  for (int i = t; i < NSAMP; i += 256){
    unsigned key = keys[i];
    if (key >= kth){
      int pos = atomicAdd(&lcnt, 1);
      if (pos < CAP){
        cand_idx[(size_t)p*CAP + pos]   = i;
        cand_score[(size_t)p*CAP + pos] = decf(key);
      }
    }
  }
  __syncthreads();
  if (t == 0) counters[p] = lcnt < CAP ? lcnt : CAP;
}

// -- radix preselect (top-64 incl. ties) -> exact f32 rescore -> radix exact
//    top-50 (node-id tie-break) -> softmax message + slab updates --
__global__ __launch_bounds__(256) void msg_kernel(
    const int* __restrict__ counters, const int* __restrict__ cand_idx,
    const float* __restrict__ cand_score, const float* __restrict__ memf,
    float* __restrict__ pc, unsigned short* __restrict__ slab,
    signed char* __restrict__ sli8, float* __restrict__ spb,
    const int* __restrict__ active)
{
  if (*active == 0) return;
  __shared__ unsigned sk[CAP]; __shared__ int si[CAP];
  __shared__ __align__(16) float gl[DIM];
  __shared__ unsigned hist[258];
  __shared__ int pn[PCAP]; __shared__ float pv[PCAP];
  __shared__ float selv[64]; __shared__ int seli[64]; __shared__ float attn[64];
  __shared__ float wv[4]; __shared__ float bc;
  __shared__ int cnt2;
  int p = blockIdx.x, t = threadIdx.x;
  int n = counters[p]; if (n > CAP) n = CAP;
  #pragma unroll
  for (int j = 0; j < 3; ++j) gl[t + j*256] = pc[(size_t)p*DIM + t + j*256];
  for (int i = t; i < CAP; i += 256){
    sk[i] = (i < n) ? encf(cand_score[(size_t)p*CAP + i]) : 0u;
    si[i] = (i < n) ? cand_idx[(size_t)p*CAP + i] : 0;
  }
  unsigned kth64 = 1u;
  if (n > PRESEL) kth64 = select_kth(sk, n, PRESEL, hist, t);
  else            __syncthreads();
  if (t == 0) cnt2 = 0;
  __syncthreads();
  for (int i = t; i < n; i += 256){
    if (sk[i] >= kth64){
      int pos = atomicAdd(&cnt2, 1);
      if (pos < PCAP) pn[pos] = si[i];
    }
  }
  __syncthreads();
  int m = cnt2 < PCAP ? cnt2 : PCAP;
  int w = t >> 6, lane = t & 63;
  for (int i = w; i < m; i += 4){
    const float* row = memf + (size_t)pn[i]*DIM;
    float s = 0.f;
    #pragma unroll
    for (int j = 0; j < 12; ++j){
      int d = lane + j*64;
      s += row[d] * gl[d];
    }
    for (int off = 32; off > 0; off >>= 1) s += __shfl_down(s, off, 64);
    if (lane == 0) pv[i] = s;
  }
  __syncthreads();
  int K = m < 50 ? m : 50;
  if (t < m) sk[t] = encf(pv[t]);
  unsigned kth50 = 1u;
  if (m > K) kth50 = select_kth(sk, m, K, hist, t);
  else       __syncthreads();
  if (t == 0) cnt2 = 0;
  __syncthreads();
  if (t < m && sk[t] > kth50){
    int pos = atomicAdd(&cnt2, 1);
    seli[pos] = pn[t]; selv[pos] = pv[t];
    sk[t] = 0u;
  }
  __syncthreads();
  if (t == 0){                             // boundary ties: smallest node id first
    int c = cnt2;
    for (int j = c; j < K; ++j){
      int best = -1, bestnode = 0x7FFFFFFF;
      for (int i = 0; i < m; ++i)
        if (sk[i] == kth50 && pn[i] < bestnode){ best = i; bestnode = pn[i]; }
      if (best < 0) break;
      seli[j] = pn[best]; selv[j] = pv[best]; sk[best] = 0u;
    }
  }
  __syncthreads();
  float v = (t < K) ? selv[t] : -3e38f;
  for (int off = 32; off > 0; off >>= 1) v = fmaxf(v, __shfl_down(v, off, 64));
  if ((t & 63) == 0) wv[t >> 6] = v;
  __syncthreads();
  if (t == 0) bc = fmaxf(fmaxf(wv[0], wv[1]), fmaxf(wv[2], wv[3]));
  __syncthreads();
  float vmax = bc;
  __syncthreads();
  if (t < K) attn[t] = __expf((selv[t] - vmax) * TAUINV);
  __syncthreads();
  if (t == 0){ float s = 0.f; for (int k = 0; k < K; ++k) s += attn[k]; bc = s; }
  __syncthreads();
  float inv = 1.0f / bc;
  int d0 = t, d1 = t + 256, d2 = t + 512;
  float a0 = gl[d0], a1 = gl[d1], a2 = gl[d2];
  for (int k = 0; k < K; ++k){
    float a = attn[k] * inv;
    const float* row = memf + (size_t)seli[k]*DIM;
    a0 += a * row[d0]; a1 += a * row[d1]; a2 += a * row[d2];
  }
  float ss = a0*a0 + a1*a1 + a2*a2;
  for (int off = 32; off > 0; off >>= 1) ss += __shfl_down(ss, off, 64);
  if ((t & 63) == 0) wv[t >> 6] = ss;
  __syncthreads();
  if (t == 0) bc = wv[0] + wv[1] + wv[2] + wv[3];
  __syncthreads();
  float rn = 1.0f / fmaxf(sqrtf(bc), 1e-12f);
  a0 *= rn; a1 *= rn; a2 *= rn;
  float* orow = pc + (size_t)p*DIM;
  orow[d0] = a0; orow[d1] = a1; orow[d2] = a2;
  float am = fmaxf(fabsf(a0), fmaxf(fabsf(a1), fabsf(a2)));
  for (int off = 32; off > 0; off >>= 1) am = fmaxf(am, __shfl_down(am, off, 64));
  __syncthreads();
  gl[d0] = a0; gl[d1] = a1; gl[d2] = a2;
  if ((t & 63) == 0) wv[t >> 6] = am;
  __syncthreads();
  if (t == 0) bc = fmaxf(fmaxf(wv[0], wv[1]), fmaxf(wv[2], wv[3]));
  __syncthreads();
  float mx = bc;
  float inv8 = (mx > 0.f) ? 127.0f / mx : 0.f;
  if (t < 96){
    int ks2 = t >> 3, c8 = t & 7;
    const float* sblk = &gl[ks2*64 + c8*8];
    uint4 u = pack8(*(const float4*)sblk, *(const float4*)(sblk + 4));
    *(uint4*)((char*)slab + (((size_t)ks2*NPATCH + p)*128) + ((size_t)(c8 ^ (p & 7))*16)) = u;
  }
  if (t < 48){
    int ks2 = t >> 2, c = t & 3;
    uint4 u = packq16(&gl[t*16], inv8);
    *(uint4*)(sli8 + ((size_t)ks2*NPATCH + p)*64 + ((c ^ ((p >> 1) & 3))*16)) = u;
  }
  if (t == 0) spb[p] = mx / 127.0f;
}

// ---------------- evidence softmax stats + weighted pooling partials ----------------
__global__ __launch_bounds__(256) void pl2_kernel(
    const unsigned* __restrict__ ev_key, const float* __restrict__ pc,
    float* __restrict__ g_part, const int* __restrict__ active)
{
  if (*active == 0) return;
  __shared__ float wv[4]; __shared__ float bc;
  int t = threadIdx.x;
  float m = -3e38f;
  for (int i = t; i < NPATCH; i += 256) m = fmaxf(m, decf(ev_key[i]));
  for (int off = 32; off > 0; off >>= 1) m = fmaxf(m, __shfl_down(m, off, 64));
  if ((t & 63) == 0) wv[t >> 6] = m;
  __syncthreads();
  if (t == 0) bc = fmaxf(fmaxf(wv[0], wv[1]), fmaxf(wv[2], wv[3]));
  __syncthreads();
  float M = bc;
  __syncthreads();
  float s = 0.f;
  for (int i = t; i < NPATCH; i += 256) s += __expf((decf(ev_key[i]) - M) * TAUINV);
  for (int off = 32; off > 0; off >>= 1) s += __shfl_down(s, off, 64);
  if ((t & 63) == 0) wv[t >> 6] = s;
  __syncthreads();
  if (t == 0) bc = wv[0] + wv[1] + wv[2] + wv[3];
  __syncthreads();
  float invS = 1.0f / bc;
  int pbase = blockIdx.x * 64;
  float a0 = 0.f, a1 = 0.f, a2 = 0.f;
  for (int i = 0; i < 64; ++i){
    int p = pbase + i;
    float wgt = __expf((decf(ev_key[p]) - M) * TAUINV) * invS;
    const float* row = pc + (size_t)p*DIM;
    a0 += wgt * row[t]; a1 += wgt * row[t + 256]; a2 += wgt * row[t + 512];
  }
  g_part[blockIdx.x*DIM + t]       = a0;
  g_part[blockIdx.x*DIM + t + 256] = a1;
  g_part[blockIdx.x*DIM + t + 512] = a2;
}

// ------- logits + entropy + commit (INIT: g=tg; else reduce g_part + norm) -------
template<bool INIT>
__global__ __launch_bounds__(256) void cm_kernel(
    const float* __restrict__ gsrc, const float* __restrict__ protos,
    float* __restrict__ logits_cur, int* __restrict__ step, int* __restrict__ active)
{
  if (!INIT && *active == 0) return;
  __shared__ __align__(16) float gl[DIM];
  __shared__ float lg[NCLS];
  __shared__ float wv[4]; __shared__ float bc;
  int t = threadIdx.x;
  if (INIT){
    #pragma unroll
    for (int j = 0; j < 3; ++j) gl[t + j*256] = gsrc[t + j*256];
  } else {
    float gv[3]; float ss = 0.f;
    #pragma unroll
    for (int j = 0; j < 3; ++j){
      int d = t + j*256;
      float s = 0.f;
      for (int b2 = 0; b2 < 32; ++b2) s += gsrc[b2*DIM + d];
      gv[j] = s; ss += s*s;
    }
    for (int off = 32; off > 0; off >>= 1) ss += __shfl_down(ss, off, 64);
    if ((t & 63) == 0) wv[t >> 6] = ss;
    __syncthreads();
    if (t == 0) bc = wv[0] + wv[1] + wv[2] + wv[3];
    __syncthreads();
    float rn = 1.0f / fmaxf(sqrtf(bc), 1e-12f);
    #pragma unroll
    for (int j = 0; j < 3; ++j) gl[t + j*256] = gv[j] * rn;
  }
  __syncthreads();
  for (int c = t; c < NCLS; c += 256){
    const float4* pr = (const float4*)(protos + (size_t)c*DIM);
    float s = 0.f;
    #pragma unroll 4
    for (int d4 = 0; d4 < DIM/4; ++d4){
      float4 pv = pr[d4];
      float4 gv = *(const float4*)&gl[d4*4];
      s += gv.x*pv.x + gv.y*pv.y + gv.z*pv.z + gv.w*pv.w;
    }
    float L = 100.0f * s;
    lg[c] = L; logits_cur[c] = L;
  }
  __syncthreads();
  float m = -3e38f;
  for (int c = t; c < NCLS; c += 256) m = fmaxf(m, lg[c]);
  for (int off = 32; off > 0; off >>= 1) m = fmaxf(m, __shfl_down(m, off, 64));
  if ((t & 63) == 0) wv[t >> 6] = m;
  __syncthreads();
  if (t == 0) bc = fmaxf(fmaxf(wv[0], wv[1]), fmaxf(wv[2], wv[3]));
  __syncthreads();
  float M = bc;
  __syncthreads();
  float s = 0.f;
  for (int c = t; c < NCLS; c += 256) s += __expf(lg[c] - M);
  for (int off = 32; off > 0; off >>= 1) s += __shfl_down(s, off, 64);
  if ((t & 63) == 0) wv[t >> 6] = s;
  __syncthreads();
  if (t == 0) bc = wv[0] + wv[1] + wv[2] + wv[3];
  __syncthreads();
  float S = bc;
  __syncthreads();
  float hp = 0.f;
  for (int c = t; c < NCLS; c += 256){
    float pcl = __expf(lg[c] - M) / S;
    hp += pcl * __logf(pcl + 1e-10f);
  }
  for (int off = 32; off > 0; off >>= 1) hp += __shfl_down(hp, off, 64);
  if ((t & 63) == 0) wv[t >> 6] = hp;
  __syncthreads();
  if (t == 0){
    float H = -(wv[0] + wv[1] + wv[2] + wv[3]);
    if (INIT){ *step = 0; *active = (H > 0.8f) ? 1 : 0; }
    else     { *step = *step + 1; *active = (H > 0.8f) ? 1 : 0; }
  }
}

// ---------------- publish ----------------
__global__ void pub_kernel(const float* __restrict__ logits_cur, const int* __restrict__ step,
                           float* __restrict__ out)
{
  int i = blockIdx.x*256 + threadIdx.x;
  if (i < NCLS) out[i] = logits_cur[i];
  else if (i == NCLS) out[i] = (float)(*step);
}

extern "C" void kernel_launch(void* const* d_in, const int* in_sizes, int n_in,
                              void* d_out, int out_size, void* d_ws, size_t ws_size,
                              hipStream_t stream)
{
  (void)in_sizes; (void)n_in; (void)out_size; (void)ws_size;
  const float* tg  = (const float*)d_in[0];   // [1,768]
  const float* tp  = (const float*)d_in[1];   // [2048,768]
  const float* mem = (const float*)d_in[2];   // [65536,768]
  const float* anc = (const float*)d_in[3];   // [1000,768]
  const float* cs  = (const float*)d_in[4];   // [1000,768]
  const float* cc  = (const float*)d_in[5];   // [1000]

  char* ws = (char*)d_ws;
  auto al = [](size_t x){ return (x + 255) & ~(size_t)255; };
  size_t OFF_PC   = 0;
  size_t OFF_PROT = al(OFF_PC   + (size_t)NPATCH*DIM*4);
  size_t OFF_ABF  = al(OFF_PROT + (size_t)NCLS*DIM*4);
  size_t OFF_MI8  = al(OFF_ABF  + (size_t)1024*DIM*2);
  size_t OFF_SA   = al(OFF_MI8  + (size_t)NMEM*DIM);
  size_t OFF_SLAB = al(OFF_SA   + (size_t)NMEM*4);
  size_t OFF_SLI8 = al(OFF_SLAB + (size_t)NPATCH*DIM*2);
  size_t OFF_SPB  = al(OFF_SLI8 + (size_t)NPATCH*DIM);
  size_t OFF_SS   = al(OFF_SPB  + (size_t)NPATCH*4);
  size_t OFF_THR  = al(OFF_SS   + (size_t)NPATCH*NSAMP*4);
  size_t OFF_CNT  = al(OFF_THR  + (size_t)NPATCH*4);
  size_t OFF_CI   = al(OFF_CNT  + (size_t)NPATCH*4);
  size_t OFF_CSC  = al(OFF_CI   + (size_t)NPATCH*CAP*4);
  size_t OFF_EV   = al(OFF_CSC  + (size_t)NPATCH*CAP*4);
  size_t OFF_GP   = al(OFF_EV   + (size_t)NPATCH*4);
  size_t OFF_LC   = al(OFF_GP   + (size_t)32*DIM*4);
  size_t OFF_STEP = al(OFF_LC   + (size_t)NCLS*4);

  float*          pc      = (float*)(ws + OFF_PC);
  float*          protos  = (float*)(ws + OFF_PROT);
  unsigned short* abf     = (unsigned short*)(ws + OFF_ABF);
  signed char*    mi8     = (signed char*)(ws + OFF_MI8);
  float*          sa      = (float*)(ws + OFF_SA);
  unsigned short* slab    = (unsigned short*)(ws + OFF_SLAB);
  signed char*    sli8    = (signed char*)(ws + OFF_SLI8);
  float*          spb     = (float*)(ws + OFF_SPB);
  float*          simss   = (float*)(ws + OFF_SS);
  float*          thr     = (float*)(ws + OFF_THR);
  int*            cnt     = (int*)(ws + OFF_CNT);
  int*            ci      = (int*)(ws + OFF_CI);
  float*          csc     = (float*)(ws + OFF_CSC);
  unsigned*       evk     = (unsigned*)(ws + OFF_EV);
  float*          gp      = (float*)(ws + OFF_GP);
  float*          lc      = (float*)(ws + OFF_LC);
  int*            stepp   = (int*)(ws + OFF_STEP);
  int*            activep = stepp + 1;

  proto_kernel<<<1024, 256, 0, stream>>>(anc, cs, cc, protos, abf);
  prep_patches<<<(NPATCH*DIM/4)/256, 256, 0, stream>>>(tp, pc);
  conv_i8_kernel<<<NMEM/8, 512, 0, stream>>>(mem, mi8, sa);
  cm_kernel<true><<<1, 256, 0, stream>>>(tg, protos, lc, stepp, activep);
  slab_init<<<NPATCH, 256, 0, stream>>>(pc, slab, sli8, spb);

  for (int it = 0; it < 3; ++it){
    gemm8_kernel<1,1><<<(NSAMP/128)*16, 256, 0, stream>>>(
        mi8, sa, 0, sli8, spb, thr, cnt, ci, csc, simss, activep);
    thresh_kernel<<<NPATCH, 256, 0, stream>>>(simss, thr, cnt, ci, csc, evk, activep);
    gemm8_kernel<0,4><<<((NMEM-NSAMP)/512)*16, 256, 0, stream>>>(
        mi8, sa, NSAMP, sli8, spb, thr, cnt, ci, csc, simss, activep);
    msg_kernel<<<NPATCH, 256, 0, stream>>>(cnt, ci, csc, mem, pc, slab, sli8, spb, activep);
    gemm_ev_kernel<<<(1024/128)*16, 256, 0, stream>>>(abf, slab, evk, activep);
    pl2_kernel<<<32, 256, 0, stream>>>(evk, pc, gp, activep);
    cm_kernel<false><<<1, 256, 0, stream>>>(gp, protos, lc, stepp, activep);
  }
  pub_kernel<<<4, 256, 0, stream>>>(lc, stepp, (float*)d_out);
}